// Round 2
// baseline (267.489 us; speedup 1.0000x reference)
//
#include <hip/hip_runtime.h>
#include <hip/hip_bf16.h>
#include <cstdint>

#define B_ 4
#define T_ 2048
#define C_ 1024
#define H_ 16
#define D_ 64

// GEMM tile geometry (both GEMMs): 256x128, BK=64, 8 waves (4M x 2N), 64x64/wave
#define BM 256
#define BN 128
#define BK 64
#define ASZ (BM * BK)   // u16 elems per A buffer = 16384 (32 KiB)
#define BSZ (BN * BK)   // u16 elems per B buffer =  8192 (16 KiB)

typedef __bf16 bf16x8 __attribute__((ext_vector_type(8)));
typedef float f32x4 __attribute__((ext_vector_type(4)));

static __device__ __forceinline__ float bf2f(unsigned short u) {
    union { unsigned int i; float f; } w;
    w.i = ((unsigned int)u) << 16;
    return w.f;
}
static __device__ __forceinline__ unsigned short f2bf(float f) {
    unsigned int i = __float_as_uint(f);
    unsigned int r = (i + 0x7FFFu + ((i >> 16) & 1u)) >> 16;
    return (unsigned short)r;
}
static __device__ __forceinline__ float exp2_fast(float x) {
    float r;
    asm("v_exp_f32 %0, %1" : "=v"(r) : "v"(x));
    return r;
}

// async global->LDS, 16B per lane (HW: LDS dest = wave-uniform base + lane*16)
static __device__ __forceinline__ void gl_lds16(const unsigned short* g,
                                                unsigned short* l) {
    __builtin_amdgcn_global_load_lds(
        (const __attribute__((address_space(1))) unsigned int*)g,
        (__attribute__((address_space(3))) unsigned int*)l, 16, 0, 0);
}

// ---------------------------------------------------------------------------
// One-time prep: fp32 -> bf16 convert (n % 8 == 0)
// ---------------------------------------------------------------------------
__global__ __launch_bounds__(256)
void convert_f32_bf16(const float* __restrict__ in,
                      unsigned short* __restrict__ out, int n) {
    int i = (blockIdx.x * 256 + threadIdx.x) * 8;
    if (i < n) {
        float4 a = *(const float4*)(in + i);
        float4 b = *(const float4*)(in + i + 4);
        ushort4 s0 = {f2bf(a.x), f2bf(a.y), f2bf(a.z), f2bf(a.w)};
        ushort4 s1 = {f2bf(b.x), f2bf(b.y), f2bf(b.z), f2bf(b.w)};
        *(ushort4*)(out + i) = s0;
        *(ushort4*)(out + i + 4) = s1;
    }
}

// ---------------------------------------------------------------------------
// One-time prep: fp32 [R][Cc] -> bf16 [Cc][R] transpose
// ---------------------------------------------------------------------------
__global__ void transpose_f32_bf16(const float* __restrict__ in,
                                   unsigned short* __restrict__ out,
                                   int R, int Cc) {
    __shared__ unsigned short tile[32][33];
    int c0 = blockIdx.x * 32;
    int r0 = blockIdx.y * 32;
    int tx = threadIdx.x, ty = threadIdx.y;
    #pragma unroll
    for (int i = ty; i < 32; i += 8)
        tile[i][tx] = f2bf(in[(size_t)(r0 + i) * Cc + c0 + tx]);
    __syncthreads();
    #pragma unroll
    for (int i = ty; i < 32; i += 8)
        out[(size_t)(c0 + i) * R + r0 + tx] = tile[tx][i];
}

// ---------------------------------------------------------------------------
// GEMM1 (fused, fine-phase pipelined): [M x 3C] = A[M][C] @ w_attn_t^T + b
// Per K-tile: 2 phases, each {8 ds_read ∥ 3 gl_lds -> barrier -> lgkm(0) ->
// setprio(1) 16 MFMA setprio(0) -> barrier}; vmcnt(6) once per tile.
// Triple-buffered LDS, XOR-swizzled chunks, XCD-aware block swizzle.
//  - q cols (<C):    *qscale, bf16 -> qkv[row][2C] at col
//  - k cols (C..2C): bf16 -> qkv[row][2C] at col
//  - v cols (>=2C):  bf16 -> vt[(b*H+h)][d][T] (transposed store)
// ---------------------------------------------------------------------------
__global__ __launch_bounds__(512)
void gemm_qkv(const unsigned short* __restrict__ A,
              const unsigned short* __restrict__ Bt,
              const float* __restrict__ bias,
              unsigned short* __restrict__ qkv,
              unsigned short* __restrict__ vt,
              int M, float qscale) {
    const int K = C_;
    __shared__ __align__(16) unsigned short Ab[3 * ASZ];   // 96 KiB
    __shared__ __align__(16) unsigned short Bb[3 * BSZ];   // 48 KiB

    int tid = threadIdx.x;
    int nwg = gridDim.x * gridDim.y;
    int flat = blockIdx.y * gridDim.x + blockIdx.x;
    int swz = (flat & 7) * (nwg >> 3) + (flat >> 3);
    int bx = swz % gridDim.x;
    int by = swz / gridDim.x;
    int row0 = by * BM;
    int col0 = bx * BN;

    int wave = tid >> 6, lane = tid & 63;
    int wm = wave >> 1, wn = wave & 1;          // 4M x 2N wave grid
    int m16 = lane & 15, quad = lane >> 4;

    // staging: LDS swizzled layout, phys chunk p <- logical chunk p^(row&7),
    // via pre-swizzled GLOBAL source (LDS dest stays linear for gl_lds).
    int arow = tid >> 3;                         // 0..63
    int achk = (tid & 7) ^ (arow & 7);
    const unsigned short* aps = A + (size_t)(row0 + arow) * K + achk * 8;
    const unsigned short* bps = Bt + (size_t)(col0 + arow) * K + achk * 8;
    unsigned short* adst = Ab + tid * 8;
    unsigned short* bdst = Bb + tid * 8;

    f32x4 acc[4][4];
    #pragma unroll
    for (int i = 0; i < 4; ++i)
        #pragma unroll
        for (int j = 0; j < 4; ++j)
            acc[i][j] = (f32x4){0.f, 0.f, 0.f, 0.f};

    // half=0: A rows 0,1 + B row 0; half=1: A rows 2,3 + B row 1
    auto STAGE_H = [&](int koff, int oa, int ob, int half) {
        if (half == 0) {
            gl_lds16(aps + (size_t)(0 * 64) * K + koff, adst + oa + 0 * 4096);
            gl_lds16(aps + (size_t)(1 * 64) * K + koff, adst + oa + 1 * 4096);
            gl_lds16(bps + (size_t)(0 * 64) * K + koff, bdst + ob + 0 * 4096);
        } else {
            gl_lds16(aps + (size_t)(2 * 64) * K + koff, adst + oa + 2 * 4096);
            gl_lds16(aps + (size_t)(3 * 64) * K + koff, adst + oa + 3 * 4096);
            gl_lds16(bps + (size_t)(1 * 64) * K + koff, bdst + ob + 1 * 4096);
        }
    };

    // read-side swizzle: chunk (kh*4+quad) ^ (m16&7)
    int rbA = wm * 64 + m16;
    int rbB = wn * 64 + m16;
    int pc0 = ((0 + quad) ^ (m16 & 7)) * 8;
    int pc1 = ((4 + quad) ^ (m16 & 7)) * 8;

    // prologue: tiles 0,1 in flight; wait tile 0 only
    STAGE_H(0, 0, 0, 0);
    STAGE_H(0, 0, 0, 1);
    STAGE_H(BK, ASZ, BSZ, 0);
    STAGE_H(BK, ASZ, BSZ, 1);
    asm volatile("s_waitcnt vmcnt(6)" ::: "memory");
    __builtin_amdgcn_s_barrier();

    int oa0 = 0, oa1 = ASZ, oa2 = 2 * ASZ;
    int ob0 = 0, ob1 = BSZ, ob2 = 2 * BSZ;
    const int NT = K / BK;   // 16
    for (int t = 0; t < NT; ++t) {
        bool st = (t + 2 < NT);
        // ---------------- phase A (k-half 0) ----------------
        {
            bf16x8 af[4], bfr[4];
            #pragma unroll
            for (int i = 0; i < 4; ++i)
                af[i] = *(const bf16x8*)(Ab + oa0 + (rbA + i * 16) * 64 + pc0);
            #pragma unroll
            for (int j = 0; j < 4; ++j)
                bfr[j] = *(const bf16x8*)(Bb + ob0 + (rbB + j * 16) * 64 + pc0);
            if (st) STAGE_H((t + 2) * BK, oa2, ob2, 0);
            __builtin_amdgcn_s_barrier();
            asm volatile("s_waitcnt lgkmcnt(0)" ::: "memory");
            __builtin_amdgcn_sched_barrier(0);
            __builtin_amdgcn_s_setprio(1);
            #pragma unroll
            for (int i = 0; i < 4; ++i)
                #pragma unroll
                for (int j = 0; j < 4; ++j)
                    acc[i][j] = __builtin_amdgcn_mfma_f32_16x16x32_bf16(
                        af[i], bfr[j], acc[i][j], 0, 0, 0);
            __builtin_amdgcn_s_setprio(0);
            __builtin_amdgcn_sched_barrier(0);
            __builtin_amdgcn_s_barrier();
        }
        // ---------------- phase B (k-half 1) ----------------
        {
            bf16x8 af[4], bfr[4];
            #pragma unroll
            for (int i = 0; i < 4; ++i)
                af[i] = *(const bf16x8*)(Ab + oa0 + (rbA + i * 16) * 64 + pc1);
            #pragma unroll
            for (int j = 0; j < 4; ++j)
                bfr[j] = *(const bf16x8*)(Bb + ob0 + (rbB + j * 16) * 64 + pc1);
            if (st) STAGE_H((t + 2) * BK, oa2, ob2, 1);
            if (t + 1 < NT) {
                if (st) asm volatile("s_waitcnt vmcnt(6)" ::: "memory");
                else    asm volatile("s_waitcnt vmcnt(0)" ::: "memory");
            }
            __builtin_amdgcn_s_barrier();
            asm volatile("s_waitcnt lgkmcnt(0)" ::: "memory");
            __builtin_amdgcn_sched_barrier(0);
            __builtin_amdgcn_s_setprio(1);
            #pragma unroll
            for (int i = 0; i < 4; ++i)
                #pragma unroll
                for (int j = 0; j < 4; ++j)
                    acc[i][j] = __builtin_amdgcn_mfma_f32_16x16x32_bf16(
                        af[i], bfr[j], acc[i][j], 0, 0, 0);
            __builtin_amdgcn_s_setprio(0);
            __builtin_amdgcn_sched_barrier(0);
            if (t + 1 < NT) __builtin_amdgcn_s_barrier();
        }
        int x;
        x = oa0; oa0 = oa1; oa1 = oa2; oa2 = x;
        x = ob0; ob0 = ob1; ob1 = ob2; ob2 = x;
    }
    __syncthreads();   // full drain once; Ab reused as epilogue scratch

    // ---- epilogue (per-wave 64x64 tile via wave-private LDS roundtrip) ----
    float bv[4];
    #pragma unroll
    for (int j = 0; j < 4; ++j)
        bv[j] = bias[col0 + wn * 64 + j * 16 + m16];

    unsigned short* wbuf = Ab + wave * 2048;   // 4 KiB per wave, 8 waves
    bool isV = (col0 >= 2 * C_);
    float sc = (col0 < C_) ? qscale : 1.0f;
    int b_loc = row0 >> 11;            // batch index (T=2048, 256 | T)
    int trow0 = (row0 & 2047) + wm * 64;

    #pragma unroll
    for (int sub = 0; sub < 4; ++sub) {
        int i0 = (sub >> 1) << 1;      // 0,0,2,2
        int j0 = (sub & 1) << 1;       // 0,2,0,2
        #pragma unroll
        for (int jj = 0; jj < 2; ++jj) {
            #pragma unroll
            for (int ii = 0; ii < 2; ++ii) {
                #pragma unroll
                for (int rr = 0; rr < 4; ++rr) {
                    int rl = ii * 16 + quad * 4 + rr;
                    int cl = jj * 16 + m16;
                    unsigned short hv =
                        f2bf((acc[i0 + ii][j0 + jj][rr] + bv[j0 + jj]) * sc);
                    if (!isV) wbuf[rl * 40 + cl] = hv;      // [row][col]
                    else      wbuf[cl * 40 + rl] = hv;      // [col][row]
                }
            }
        }
        __builtin_amdgcn_sched_barrier(0);
        if (!isV) {
            #pragma unroll
            for (int it = 0; it < 4; ++it) {
                int rl = it * 8 + (lane >> 3);
                int cc = (lane & 7) << 2;
                uint2 v2 = *(const uint2*)&wbuf[rl * 40 + cc];
                int rowg = row0 + wm * 64 + i0 * 16 + rl;
                int colg = col0 + wn * 64 + j0 * 16 + cc;
                *(uint2*)&qkv[(size_t)rowg * (2 * C_) + colg] = v2;
            }
        } else {
            int head = ((col0 - 2 * C_) + wn * 64) >> 6;
            unsigned short* vtb =
                vt + (size_t)((b_loc * H_ + head) * 64) * T_;
            #pragma unroll
            for (int it = 0; it < 4; ++it) {
                int dsub = it * 8 + (lane >> 3);
                int tc = (lane & 7) << 2;
                uint2 v2 = *(const uint2*)&wbuf[dsub * 40 + tc];
                int d = j0 * 16 + dsub;
                int tg = trow0 + i0 * 16 + tc;
                *(uint2*)&vtb[(size_t)d * T_ + tg] = v2;
            }
        }
        __builtin_amdgcn_sched_barrier(0);
    }
}

// ---------------------------------------------------------------------------
// GEMM2 (fine-phase pipelined): out[M][C] fp32 = A[M][K=C] (bf16, lda) @ Bt^T
// ---------------------------------------------------------------------------
__global__ __launch_bounds__(512)
void gemm_out(const unsigned short* __restrict__ A, int lda,
              const unsigned short* __restrict__ Bt,
              const float* __restrict__ bias,
              float* __restrict__ Cmat,
              int M, int N, int K) {
    __shared__ __align__(16) unsigned short Ab[3 * ASZ];
    __shared__ __align__(16) unsigned short Bb[3 * BSZ];

    int tid = threadIdx.x;
    int nwg = gridDim.x * gridDim.y;
    int flat = blockIdx.y * gridDim.x + blockIdx.x;
    int swz = (flat & 7) * (nwg >> 3) + (flat >> 3);
    int bx = swz % gridDim.x;
    int by = swz / gridDim.x;
    int row0 = by * BM;
    int col0 = bx * BN;

    int wave = tid >> 6, lane = tid & 63;
    int wm = wave >> 1, wn = wave & 1;
    int m16 = lane & 15, quad = lane >> 4;

    int arow = tid >> 3;
    int achk = (tid & 7) ^ (arow & 7);
    const unsigned short* aps = A + (size_t)(row0 + arow) * lda + achk * 8;
    const unsigned short* bps = Bt + (size_t)(col0 + arow) * K + achk * 8;
    unsigned short* adst = Ab + tid * 8;
    unsigned short* bdst = Bb + tid * 8;

    f32x4 acc[4][4];
    #pragma unroll
    for (int i = 0; i < 4; ++i)
        #pragma unroll
        for (int j = 0; j < 4; ++j)
            acc[i][j] = (f32x4){0.f, 0.f, 0.f, 0.f};

    auto STAGE_H = [&](int koff, int oa, int ob, int half) {
        if (half == 0) {
            gl_lds16(aps + (size_t)(0 * 64) * lda + koff, adst + oa + 0 * 4096);
            gl_lds16(aps + (size_t)(1 * 64) * lda + koff, adst + oa + 1 * 4096);
            gl_lds16(bps + (size_t)(0 * 64) * K + koff, bdst + ob + 0 * 4096);
        } else {
            gl_lds16(aps + (size_t)(2 * 64) * lda + koff, adst + oa + 2 * 4096);
            gl_lds16(aps + (size_t)(3 * 64) * lda + koff, adst + oa + 3 * 4096);
            gl_lds16(bps + (size_t)(1 * 64) * K + koff, bdst + ob + 1 * 4096);
        }
    };

    int rbA = wm * 64 + m16;
    int rbB = wn * 64 + m16;
    int pc0 = ((0 + quad) ^ (m16 & 7)) * 8;
    int pc1 = ((4 + quad) ^ (m16 & 7)) * 8;

    STAGE_H(0, 0, 0, 0);
    STAGE_H(0, 0, 0, 1);
    STAGE_H(BK, ASZ, BSZ, 0);
    STAGE_H(BK, ASZ, BSZ, 1);
    asm volatile("s_waitcnt vmcnt(6)" ::: "memory");
    __builtin_amdgcn_s_barrier();

    int oa0 = 0, oa1 = ASZ, oa2 = 2 * ASZ;
    int ob0 = 0, ob1 = BSZ, ob2 = 2 * BSZ;
    const int NT = C_ / BK;
    for (int t = 0; t < NT; ++t) {
        bool st = (t + 2 < NT);
        // phase A
        {
            bf16x8 af[4], bfr[4];
            #pragma unroll
            for (int i = 0; i < 4; ++i)
                af[i] = *(const bf16x8*)(Ab + oa0 + (rbA + i * 16) * 64 + pc0);
            #pragma unroll
            for (int j = 0; j < 4; ++j)
                bfr[j] = *(const bf16x8*)(Bb + ob0 + (rbB + j * 16) * 64 + pc0);
            if (st) STAGE_H((t + 2) * BK, oa2, ob2, 0);
            __builtin_amdgcn_s_barrier();
            asm volatile("s_waitcnt lgkmcnt(0)" ::: "memory");
            __builtin_amdgcn_sched_barrier(0);
            __builtin_amdgcn_s_setprio(1);
            #pragma unroll
            for (int i = 0; i < 4; ++i)
                #pragma unroll
                for (int j = 0; j < 4; ++j)
                    acc[i][j] = __builtin_amdgcn_mfma_f32_16x16x32_bf16(
                        af[i], bfr[j], acc[i][j], 0, 0, 0);
            __builtin_amdgcn_s_setprio(0);
            __builtin_amdgcn_sched_barrier(0);
            __builtin_amdgcn_s_barrier();
        }
        // phase B
        {
            bf16x8 af[4], bfr[4];
            #pragma unroll
            for (int i = 0; i < 4; ++i)
                af[i] = *(const bf16x8*)(Ab + oa0 + (rbA + i * 16) * 64 + pc1);
            #pragma unroll
            for (int j = 0; j < 4; ++j)
                bfr[j] = *(const bf16x8*)(Bb + ob0 + (rbB + j * 16) * 64 + pc1);
            if (st) STAGE_H((t + 2) * BK, oa2, ob2, 1);
            if (t + 1 < NT) {
                if (st) asm volatile("s_waitcnt vmcnt(6)" ::: "memory");
                else    asm volatile("s_waitcnt vmcnt(0)" ::: "memory");
            }
            __builtin_amdgcn_s_barrier();
            asm volatile("s_waitcnt lgkmcnt(0)" ::: "memory");
            __builtin_amdgcn_sched_barrier(0);
            __builtin_amdgcn_s_setprio(1);
            #pragma unroll
            for (int i = 0; i < 4; ++i)
                #pragma unroll
                for (int j = 0; j < 4; ++j)
                    acc[i][j] = __builtin_amdgcn_mfma_f32_16x16x32_bf16(
                        af[i], bfr[j], acc[i][j], 0, 0, 0);
            __builtin_amdgcn_s_setprio(0);
            __builtin_amdgcn_sched_barrier(0);
            if (t + 1 < NT) __builtin_amdgcn_s_barrier();
        }
        int x;
        x = oa0; oa0 = oa1; oa1 = oa2; oa2 = x;
        x = ob0; ob0 = ob1; ob1 = ob2; ob2 = x;
    }

    #pragma unroll
    for (int j = 0; j < 4; ++j) {
        int col = col0 + wn * 64 + j * 16 + m16;
        float bvv = bias[col];
        #pragma unroll
        for (int i = 0; i < 4; ++i) {
            int row = row0 + wm * 64 + i * 16 + quad * 4;
            #pragma unroll
            for (int rr = 0; rr < 4; ++rr)
                Cmat[(size_t)(row + rr) * N + col] = acc[i][j][rr] + bvv;
        }
    }
}

// ---------------------------------------------------------------------------
// MFMA causal flash attention over qk[row][2C] (q|k), V from vt[bh][64][T].
// Output in-place over q section. exp2-softmax, no max subtraction.
// ---------------------------------------------------------------------------
__global__ __launch_bounds__(256)
void attn_mfma(unsigned short* __restrict__ qkv,
               const unsigned short* __restrict__ vt) {
    __shared__ __align__(16) unsigned short Ks[2][64][80];   // [buf][key][d]
    __shared__ __align__(16) unsigned short Vs[2][64][80];   // [buf][d][key]
    __shared__ __align__(16) unsigned short Pb[4][16][72];   // per-wave [qr][key]

    int bh = blockIdx.x;
    int b = bh >> 4, h = bh & 15;
    int qb = (T_ / 64 - 1) - blockIdx.y;     // reversed: big blocks first
    int tid = threadIdx.x;
    int wave = tid >> 6;
    int lane = tid & 63;
    int m16 = lane & 15, quad = lane >> 4;

    const size_t rs = 2 * C_;
    unsigned short* base = qkv + (size_t)b * T_ * rs + h * 64;
    const unsigned short* kb0 = base + C_;
    const unsigned short* vtb = vt + (size_t)bh * 64 * T_;

    int qrow = qb * 64 + wave * 16 + m16;
    const unsigned short* qp = base + (size_t)qrow * rs;
    bf16x8 qf0 = *(const bf16x8*)(qp + quad * 8);
    bf16x8 qf1 = *(const bf16x8*)(qp + 32 + quad * 8);

    f32x4 o[4];
    #pragma unroll
    for (int dt = 0; dt < 4; ++dt) o[dt] = (f32x4){0.f, 0.f, 0.f, 0.f};
    float lrow[4] = {0.f, 0.f, 0.f, 0.f};

    int qg0 = qb * 64 + wave * 16 + quad * 4;
    int ntiles = qb + 1;

    int kkey = tid >> 3, kdc = (tid & 7) << 3;
    int vd   = tid >> 3, vkc = (tid & 7) << 3;

    uint4 ra  = *(const uint4*)(kb0 + (size_t)kkey * rs + kdc);
    uint4 rb  = *(const uint4*)(kb0 + (size_t)(kkey + 32) * rs + kdc);
    uint4 rva = *(const uint4*)(vtb + (size_t)vd * T_ + vkc);
    uint4 rvb = *(const uint4*)(vtb + (size_t)(vd + 32) * T_ + vkc);
    *(uint4*)&Ks[0][kkey][kdc]      = ra;
    *(uint4*)&Ks[0][kkey + 32][kdc] = rb;
    *(uint4*)&Vs[0][vd][vkc]        = rva;
    *(uint4*)&Vs[0][vd + 32][vkc]   = rvb;
    if (ntiles > 1) {
        const unsigned short* kn = kb0 + (size_t)64 * rs;
        ra  = *(const uint4*)(kn + (size_t)kkey * rs + kdc);
        rb  = *(const uint4*)(kn + (size_t)(kkey + 32) * rs + kdc);
        rva = *(const uint4*)(vtb + (size_t)vd * T_ + 64 + vkc);
        rvb = *(const uint4*)(vtb + (size_t)(vd + 32) * T_ + 64 + vkc);
    }
    __syncthreads();

    for (int kt = 0; kt < ntiles; ++kt) {
        int cur = kt & 1;

        f32x4 s[4];
        #pragma unroll
        for (int st = 0; st < 4; ++st) {
            f32x4 acc = (f32x4){0.f, 0.f, 0.f, 0.f};
            bf16x8 k0 = *(const bf16x8*)&Ks[cur][st * 16 + m16][quad * 8];
            bf16x8 k1 = *(const bf16x8*)&Ks[cur][st * 16 + m16][32 + quad * 8];
            acc = __builtin_amdgcn_mfma_f32_16x16x32_bf16(qf0, k0, acc, 0, 0, 0);
            acc = __builtin_amdgcn_mfma_f32_16x16x32_bf16(qf1, k1, acc, 0, 0, 0);
            s[st] = acc;
        }

        if (kt == qb) {
            #pragma unroll
            for (int st = 0; st < 4; ++st) {
                int kg = kt * 64 + st * 16 + m16;
                #pragma unroll
                for (int r = 0; r < 4; ++r)
                    if (kg > qg0 + r) s[st][r] = -1.0e30f;
            }
        }

        #pragma unroll
        for (int st = 0; st < 4; ++st) {
            #pragma unroll
            for (int r = 0; r < 4; ++r) {
                float p = exp2_fast(s[st][r]);
                lrow[r] += p;
                Pb[wave][quad * 4 + r][st * 16 + m16] = f2bf(p);
            }
        }
        __builtin_amdgcn_sched_barrier(0);

        #pragma unroll
        for (int s2 = 0; s2 < 2; ++s2) {
            bf16x8 pa = *(const bf16x8*)&Pb[wave][m16][s2 * 32 + quad * 8];
            #pragma unroll
            for (int dt = 0; dt < 4; ++dt) {
                bf16x8 vv = *(const bf16x8*)&Vs[cur][dt * 16 + m16][s2 * 32 + quad * 8];
                o[dt] = __builtin_amdgcn_mfma_f32_16x16x32_bf16(pa, vv, o[dt], 0, 0, 0);
            }
        }

        if (kt + 1 < ntiles) {
            int nxt = (kt + 1) & 1;
            *(uint4*)&Ks[nxt][kkey][kdc]      = ra;
            *(uint4*)&Ks[nxt][kkey + 32][kdc] = rb;
            *(uint4*)&Vs[nxt][vd][vkc]        = rva;
            *(uint4*)&Vs[nxt][vd + 32][vkc]   = rvb;
            if (kt + 2 < ntiles) {
                const unsigned short* kn = kb0 + (size_t)((kt + 2) * 64) * rs;
                ra  = *(const uint4*)(kn + (size_t)kkey * rs + kdc);
                rb  = *(const uint4*)(kn + (size_t)(kkey + 32) * rs + kdc);
                rva = *(const uint4*)(vtb + (size_t)vd * T_ + (kt + 2) * 64 + vkc);
                rvb = *(const uint4*)(vtb + (size_t)(vd + 32) * T_ + (kt + 2) * 64 + vkc);
            }
        }
        __syncthreads();
    }

    float lf[4];
    #pragma unroll
    for (int r = 0; r < 4; ++r) lf[r] = lrow[r];
    #pragma unroll
    for (int off = 1; off <= 8; off <<= 1)
        #pragma unroll
        for (int r = 0; r < 4; ++r)
            lf[r] += __shfl_xor(lf[r], off);

    #pragma unroll
    for (int r = 0; r < 4; ++r) {
        float inv = 1.0f / lf[r];
        unsigned short* op = base + (size_t)(qg0 + r) * rs;
        #pragma unroll
        for (int dt = 0; dt < 4; ++dt)
            op[dt * 16 + m16] = f2bf(o[dt][r] * inv);
    }
}

// ---------------------------------------------------------------------------
extern "C" void kernel_launch(void* const* d_in, const int* in_sizes, int n_in,
                              void* d_out, int out_size, void* d_ws, size_t ws_size,
                              hipStream_t stream) {
    const float* x      = (const float*)d_in[0];
    const float* w_attn = (const float*)d_in[1];
    const float* b_attn = (const float*)d_in[2];
    const float* w_proj = (const float*)d_in[3];
    const float* b_proj = (const float*)d_in[4];
    float* out = (float*)d_out;

    unsigned short* ws = (unsigned short*)d_ws;
    unsigned short* xb       = ws;                               // [B*T][C]
    unsigned short* w_attn_t = xb + (size_t)B_ * T_ * C_;        // [3C][C]
    unsigned short* w_proj_t = w_attn_t + (size_t)3 * C_ * C_;   // [C][C]
    unsigned short* qkv      = w_proj_t + (size_t)C_ * C_;       // [bstep*T][2C]

    const size_t fixed_hw = (size_t)B_ * T_ * C_ + 4 * (size_t)C_ * C_;
    const size_t per_b_hw = (size_t)T_ * 2 * C_ + (size_t)H_ * 64 * T_; // qk + vt
    int bstep = (ws_size >= (fixed_hw + (size_t)B_ * per_b_hw) * sizeof(unsigned short))
                ? B_ : 1;

    int nx = B_ * T_ * C_;
    convert_f32_bf16<<<nx / 2048, 256, 0, stream>>>(x, xb, nx);
    transpose_f32_bf16<<<dim3(3 * C_ / 32, C_ / 32), dim3(32, 8), 0, stream>>>(
        w_attn, w_attn_t, C_, 3 * C_);
    transpose_f32_bf16<<<dim3(C_ / 32, C_ / 32), dim3(32, 8), 0, stream>>>(
        w_proj, w_proj_t, C_, C_);

    // q pre-scale: (1/sqrt(D)) * log2(e)  -> softmax via exp2, no max-sub
    const float QSCALE = 0.125f * 1.44269504088896341f;

    for (int b0 = 0; b0 < B_; b0 += bstep) {
        int M = bstep * T_;
        const unsigned short* xbb = xb + (size_t)b0 * T_ * C_;
        unsigned short* vt = qkv + (size_t)bstep * T_ * 2 * C_;  // [bstep*H][64][T]

        gemm_qkv<<<dim3(3 * C_ / BN, M / BM), 512, 0, stream>>>(
            xbb, w_attn_t, b_attn, qkv, vt, M, QSCALE);

        attn_mfma<<<dim3(bstep * H_, T_ / 64), 256, 0, stream>>>(qkv, vt);

        gemm_out<<<dim3(C_ / BN, M / BM), 512, 0, stream>>>(
            qkv, 2 * C_, w_proj_t, b_proj, out + (size_t)b0 * T_ * C_, M, C_, C_);
    }
}

// Round 3
// 265.681 us; speedup vs baseline: 1.0068x; 1.0068x over previous
//
#include <hip/hip_runtime.h>
#include <hip/hip_bf16.h>
#include <cstdint>

#define B_ 4
#define T_ 2048
#define C_ 1024
#define H_ 16
#define D_ 64

// GEMM tile geometry (both GEMMs): 256x256, BK=64, 8 waves (2M x 4N), 128x64/wave
#define BM 256
#define BN 256
#define BK 64
#define NT 16   // K / BK = 1024 / 64

typedef __bf16 bf16x8 __attribute__((ext_vector_type(8)));
typedef float f32x4 __attribute__((ext_vector_type(4)));

static __device__ __forceinline__ unsigned short f2bf(float f) {
    unsigned int i = __float_as_uint(f);
    unsigned int r = (i + 0x7FFFu + ((i >> 16) & 1u)) >> 16;
    return (unsigned short)r;
}
static __device__ __forceinline__ float exp2_fast(float x) {
    float r;
    asm("v_exp_f32 %0, %1" : "=v"(r) : "v"(x));
    return r;
}

// async global->LDS, 16B per lane (HW: LDS dest = wave-uniform base + lane*16)
static __device__ __forceinline__ void gl_lds16(const unsigned short* g,
                                                unsigned short* l) {
    __builtin_amdgcn_global_load_lds(
        (const __attribute__((address_space(1))) unsigned int*)g,
        (__attribute__((address_space(3))) unsigned int*)l, 16, 0, 0);
}

// ---------------------------------------------------------------------------
// One-time prep: fp32 -> bf16 convert (n % 8 == 0)
// ---------------------------------------------------------------------------
__global__ __launch_bounds__(256)
void convert_f32_bf16(const float* __restrict__ in,
                      unsigned short* __restrict__ out, int n) {
    int i = (blockIdx.x * 256 + threadIdx.x) * 8;
    if (i < n) {
        float4 a = *(const float4*)(in + i);
        float4 b = *(const float4*)(in + i + 4);
        ushort4 s0 = {f2bf(a.x), f2bf(a.y), f2bf(a.z), f2bf(a.w)};
        ushort4 s1 = {f2bf(b.x), f2bf(b.y), f2bf(b.z), f2bf(b.w)};
        *(ushort4*)(out + i) = s0;
        *(ushort4*)(out + i + 4) = s1;
    }
}

// ---------------------------------------------------------------------------
// One-time prep: fp32 [R][Cc] -> bf16 [Cc][R] transpose
// ---------------------------------------------------------------------------
__global__ void transpose_f32_bf16(const float* __restrict__ in,
                                   unsigned short* __restrict__ out,
                                   int R, int Cc) {
    __shared__ unsigned short tile[32][33];
    int c0 = blockIdx.x * 32;
    int r0 = blockIdx.y * 32;
    int tx = threadIdx.x, ty = threadIdx.y;
    #pragma unroll
    for (int i = ty; i < 32; i += 8)
        tile[i][tx] = f2bf(in[(size_t)(r0 + i) * Cc + c0 + tx]);
    __syncthreads();
    #pragma unroll
    for (int i = ty; i < 32; i += 8)
        out[(size_t)(c0 + i) * R + r0 + tx] = tile[tx][i];
}

// ===========================================================================
// Shared GEMM machinery (macros; 256x256 tile, 4-quadrant phases per K-tile)
//
// LDS (u16 offsets), 128 KiB total:
//   A(buf,rh) region: (buf*2+rh)*8192 ; inside: wm*4096 + rr*64 + chunk*8
//     holds rows { row0 + wm*128 + rh*64 + rr }, rr in 0..63, wm in 0..1
//   B(buf,ch) region: 32768 + (buf*2+ch)*8192 ; inside: wn*2048 + cc*64 + chunk*8
//     holds cols { col0 + wn*64 + ch*32 + cc }, cc in 0..31, wn in 0..3
// chunk is XOR-swizzled: phys = logical ^ (row&7), applied on the GLOBAL
// source side at staging (LDS dest stays linear for global_load_lds) and on
// the read side.  Group order per K-tile: r0=A.rh0, r1=B.ch0, r2=A.rh1,
// r3=B.ch1 (consumption order: P1 needs r0+r1, P2 r2, P3 r3, P4 none).
// ===========================================================================

#define LDA_RH(RH, BUF) do {                                                  \
    const unsigned short* _p = smem + ((BUF) * 2 + (RH)) * 8192 + aRd;        \
    _Pragma("unroll")                                                         \
    for (int fi = 0; fi < 4; ++fi) {                                          \
        afr[RH][fi][0] = *(const bf16x8*)(_p + fi * 1024 + pc0);              \
        afr[RH][fi][1] = *(const bf16x8*)(_p + fi * 1024 + pc1);              \
    }                                                                         \
} while (0)

#define LDB_CH(CH, BUF) do {                                                  \
    const unsigned short* _p = smem + 32768 + ((BUF) * 2 + (CH)) * 8192 + bRd;\
    _Pragma("unroll")                                                         \
    for (int fj = 0; fj < 2; ++fj) {                                          \
        bfr[fj][0] = *(const bf16x8*)(_p + fj * 1024 + pc0);                  \
        bfr[fj][1] = *(const bf16x8*)(_p + fj * 1024 + pc1);                  \
    }                                                                         \
} while (0)

#define MFMA_QUAD(RH, CH) do {                                                \
    _Pragma("unroll")                                                         \
    for (int fi = 0; fi < 4; ++fi)                                            \
    _Pragma("unroll")                                                         \
    for (int fj = 0; fj < 2; ++fj) {                                          \
        acc[RH][fi][CH][fj] = __builtin_amdgcn_mfma_f32_16x16x32_bf16(        \
            afr[RH][fi][0], bfr[fj][0], acc[RH][fi][CH][fj], 0, 0, 0);        \
        acc[RH][fi][CH][fj] = __builtin_amdgcn_mfma_f32_16x16x32_bf16(        \
            afr[RH][fi][1], bfr[fj][1], acc[RH][fi][CH][fj], 0, 0, 0);        \
    }                                                                         \
} while (0)

#define PHASE_SYNC_MFMA(RH, CH) do {                                          \
    __builtin_amdgcn_s_barrier();                                             \
    asm volatile("s_waitcnt lgkmcnt(0)" ::: "memory");                        \
    __builtin_amdgcn_sched_barrier(0);                                        \
    __builtin_amdgcn_s_setprio(1);                                            \
    MFMA_QUAD(RH, CH);                                                        \
    __builtin_amdgcn_s_setprio(0);                                            \
    __builtin_amdgcn_sched_barrier(0);                                        \
} while (0)

// common per-thread setup + staging lambda + main K loop (K = 1024)
#define GEMM_CORE(APTR, LDA_STRIDE, BTPTR)                                    \
    int tid = threadIdx.x;                                                    \
    int nwg = gridDim.x * gridDim.y;                                          \
    int flat = blockIdx.y * gridDim.x + blockIdx.x;                           \
    int swz = (flat & 7) * (nwg >> 3) + (flat >> 3);                          \
    int bx = swz % gridDim.x;                                                 \
    int by = swz / gridDim.x;                                                 \
    int row0 = by * BM;                                                       \
    int col0 = bx * BN;                                                       \
    int wave = tid >> 6, lane = tid & 63;                                     \
    int wm = wave >> 2, wn = wave & 3;                                        \
    int m16 = lane & 15, quad = lane >> 4;                                    \
    int srow = tid >> 3;                                                      \
    int kcs  = ((tid & 7) ^ (srow & 7)) * 8;                                  \
    int bcc  = (tid >> 3) & 31;                                               \
    int bwn0 = tid >> 8;                                                      \
    int aRd = wm * 4096 + m16 * 64;                                           \
    int bRd = wn * 2048 + m16 * 64;                                           \
    int pc0 = ((0 + quad) ^ (m16 & 7)) * 8;                                   \
    int pc1 = ((4 + quad) ^ (m16 & 7)) * 8;                                   \
    bf16x8 afr[2][4][2];                                                      \
    bf16x8 bfr[2][2];                                                         \
    f32x4 acc[2][4][2][2];                                                    \
    _Pragma("unroll")                                                         \
    for (int a1 = 0; a1 < 2; ++a1)                                            \
    _Pragma("unroll")                                                         \
    for (int a2 = 0; a2 < 4; ++a2)                                            \
    _Pragma("unroll")                                                         \
    for (int a3 = 0; a3 < 2; ++a3)                                            \
    _Pragma("unroll")                                                         \
    for (int a4 = 0; a4 < 2; ++a4)                                            \
        acc[a1][a2][a3][a4] = (f32x4){0.f, 0.f, 0.f, 0.f};                    \
    auto STAGE_GROUP = [&](int g) {                                           \
        if (g > 4 * NT - 1) return;                                           \
        int kt  = g >> 2;                                                     \
        int r   = g & 3;                                                      \
        int buf = kt & 1;                                                     \
        int koff = kt * BK;                                                   \
        if ((r & 1) == 0) {                                                   \
            int rh = r >> 1;                                                  \
            unsigned short* dst = smem + (buf * 2 + rh) * 8192 + tid * 8;     \
            const unsigned short* src =                                       \
                (APTR) + (size_t)(row0 + rh * 64 + srow) * (LDA_STRIDE)       \
                       + koff + kcs;                                          \
            gl_lds16(src, dst);                                               \
            gl_lds16(src + (size_t)128 * (LDA_STRIDE), dst + 4096);           \
        } else {                                                              \
            int ch = r >> 1;                                                  \
            unsigned short* dst = smem + 32768 + (buf * 2 + ch) * 8192        \
                                  + tid * 8;                                  \
            int colg = col0 + bwn0 * 64 + ch * 32 + bcc;                      \
            const unsigned short* src =                                       \
                (BTPTR) + (size_t)colg * C_ + koff + kcs;                     \
            gl_lds16(src, dst);                                               \
            gl_lds16(src + (size_t)128 * C_, dst + 4096);                     \
        }                                                                     \
    };                                                                        \
    STAGE_GROUP(0); STAGE_GROUP(1); STAGE_GROUP(2);                           \
    STAGE_GROUP(3); STAGE_GROUP(4); STAGE_GROUP(5);                           \
    asm volatile("s_waitcnt vmcnt(8)" ::: "memory");                          \
    __builtin_amdgcn_s_barrier();                                             \
    for (int t = 0; t < NT - 1; ++t) {                                        \
        int buf = t & 1;                                                      \
        int g0 = 4 * t + 6;                                                   \
        /* P1: quadrant (rh0, ch0) */                                         \
        LDA_RH(0, buf); LDB_CH(0, buf);                                       \
        STAGE_GROUP(g0);                                                      \
        PHASE_SYNC_MFMA(0, 0);                                                \
        asm volatile("s_waitcnt vmcnt(8)" ::: "memory");                      \
        __builtin_amdgcn_s_barrier();                                         \
        /* P2: (rh1, ch0) */                                                  \
        LDA_RH(1, buf);                                                       \
        STAGE_GROUP(g0 + 1);                                                  \
        PHASE_SYNC_MFMA(1, 0);                                                \
        asm volatile("s_waitcnt vmcnt(8)" ::: "memory");                      \
        __builtin_amdgcn_s_barrier();                                         \
        /* P3: (rh1, ch1) */                                                  \
        LDB_CH(1, buf);                                                       \
        STAGE_GROUP(g0 + 2);                                                  \
        PHASE_SYNC_MFMA(1, 1);                                                \
        __builtin_amdgcn_s_barrier();                                         \
        /* P4: (rh0, ch1) — no new reads */                                   \
        STAGE_GROUP(g0 + 3);                                                  \
        __builtin_amdgcn_s_barrier();                                         \
        __builtin_amdgcn_s_setprio(1);                                        \
        MFMA_QUAD(0, 1);                                                      \
        __builtin_amdgcn_s_setprio(0);                                        \
        __builtin_amdgcn_sched_barrier(0);                                    \
        if (t == NT - 2) { asm volatile("s_waitcnt vmcnt(4)" ::: "memory"); } \
        else             { asm volatile("s_waitcnt vmcnt(8)" ::: "memory"); } \
        __builtin_amdgcn_s_barrier();                                         \
    }                                                                         \
    {   /* peeled last K-tile (t = NT-1, buf = 1): drain gates 2 / 0 */       \
        LDA_RH(0, 1); LDB_CH(0, 1);                                           \
        PHASE_SYNC_MFMA(0, 0);                                                \
        asm volatile("s_waitcnt vmcnt(2)" ::: "memory");                      \
        __builtin_amdgcn_s_barrier();                                         \
        LDA_RH(1, 1);                                                         \
        PHASE_SYNC_MFMA(1, 0);                                                \
        asm volatile("s_waitcnt vmcnt(0)" ::: "memory");                      \
        __builtin_amdgcn_s_barrier();                                         \
        LDB_CH(1, 1);                                                         \
        PHASE_SYNC_MFMA(1, 1);                                                \
        __builtin_amdgcn_s_barrier();                                         \
        __builtin_amdgcn_s_setprio(1);                                        \
        MFMA_QUAD(0, 1);                                                      \
        __builtin_amdgcn_s_setprio(0);                                        \
    }                                                                         \
    __syncthreads();

// ---------------------------------------------------------------------------
// GEMM1 (fused): [M x 3C] = A[M][C] @ w_attn_t[3C][C]^T + b_attn
//  - q cols (<C):    *qscale, bf16 -> qkv[row][2C] at col
//  - k cols (C..2C): bf16 -> qkv[row][2C] at col
//  - v cols (>=2C):  bf16 -> vt[(b*H+h)][d][T] (transposed store)
// ---------------------------------------------------------------------------
__global__ __launch_bounds__(512, 2)
void gemm_qkv(const unsigned short* __restrict__ A,
              const unsigned short* __restrict__ Bt,
              const float* __restrict__ bias,
              unsigned short* __restrict__ qkv,
              unsigned short* __restrict__ vt,
              int M, float qscale) {
    __shared__ __align__(16) unsigned short smem[65536];   // 128 KiB
    GEMM_CORE(A, C_, Bt)

    // ---- epilogue: per-wave 128x64 tile = 2 x (64x64 sub-tile sets) ----
    float bv[4];
    #pragma unroll
    for (int j = 0; j < 4; ++j)
        bv[j] = bias[col0 + wn * 64 + j * 16 + m16];

    unsigned short* wbuf = smem + wave * 2048;   // 4 KiB per wave
    bool isV = (col0 >= 2 * C_);
    float sc = (col0 < C_) ? qscale : 1.0f;
    int b_loc = row0 >> 11;                      // batch (T=2048, 256|T)
    int head = isV ? ((col0 - 2 * C_ + wn * 64) >> 6) : 0;
    unsigned short* vtb = vt + (size_t)((b_loc * H_ + head) * 64) * T_;

    #pragma unroll
    for (int rh = 0; rh < 2; ++rh) {
        int rbase = row0 + wm * 128 + rh * 64;
        int trow0 = (row0 & 2047) + wm * 128 + rh * 64;
        #pragma unroll
        for (int sub = 0; sub < 4; ++sub) {
            int i0 = (sub >> 1) << 1;      // 0,0,2,2
            int j0 = (sub & 1) << 1;       // 0,2,0,2
            #pragma unroll
            for (int jj = 0; jj < 2; ++jj) {
                #pragma unroll
                for (int ii = 0; ii < 2; ++ii) {
                    #pragma unroll
                    for (int rr = 0; rr < 4; ++rr) {
                        int rl = ii * 16 + quad * 4 + rr;
                        int cl = jj * 16 + m16;
                        float av = acc[rh][i0 + ii][(j0 + jj) >> 1]
                                      [(j0 + jj) & 1][rr];
                        unsigned short hv = f2bf((av + bv[j0 + jj]) * sc);
                        if (!isV) wbuf[rl * 40 + cl] = hv;      // [row][col]
                        else      wbuf[cl * 40 + rl] = hv;      // [col][row]
                    }
                }
            }
            __builtin_amdgcn_sched_barrier(0);
            if (!isV) {
                #pragma unroll
                for (int it = 0; it < 4; ++it) {
                    int rl = it * 8 + (lane >> 3);
                    int cc2 = (lane & 7) << 2;
                    uint2 v2 = *(const uint2*)&wbuf[rl * 40 + cc2];
                    int rowg = rbase + i0 * 16 + rl;
                    int colg = col0 + wn * 64 + j0 * 16 + cc2;
                    *(uint2*)&qkv[(size_t)rowg * (2 * C_) + colg] = v2;
                }
            } else {
                #pragma unroll
                for (int it = 0; it < 4; ++it) {
                    int dsub = it * 8 + (lane >> 3);
                    int tc = (lane & 7) << 2;
                    uint2 v2 = *(const uint2*)&wbuf[dsub * 40 + tc];
                    int d = j0 * 16 + dsub;
                    int tg = trow0 + i0 * 16 + tc;
                    *(uint2*)&vtb[(size_t)d * T_ + tg] = v2;
                }
            }
            __builtin_amdgcn_sched_barrier(0);
        }
    }
}

// ---------------------------------------------------------------------------
// GEMM2: out[M][C] (fp32) = A[M][K=C] (bf16, row stride lda=2C) @ Bt^T + b
// ---------------------------------------------------------------------------
__global__ __launch_bounds__(512, 2)
void gemm_out(const unsigned short* __restrict__ A,
              const unsigned short* __restrict__ Bt,
              const float* __restrict__ bias,
              float* __restrict__ Cmat,
              int M) {
    const int N = C_;
    __shared__ __align__(16) unsigned short smem[65536];
    GEMM_CORE(A, (2 * C_), Bt)

    #pragma unroll
    for (int rh = 0; rh < 2; ++rh) {
        int rbase = row0 + wm * 128 + rh * 64;
        #pragma unroll
        for (int j = 0; j < 4; ++j) {
            int col = col0 + wn * 64 + j * 16 + m16;
            float bvv = bias[col];
            #pragma unroll
            for (int i = 0; i < 4; ++i) {
                int row = rbase + i * 16 + quad * 4;
                #pragma unroll
                for (int rr = 0; rr < 4; ++rr)
                    Cmat[(size_t)(row + rr) * N + col] =
                        acc[rh][i][j >> 1][j & 1][rr] + bvv;
            }
        }
    }
}

// ---------------------------------------------------------------------------
// MFMA causal flash attention over qk[row][2C] (q|k), V from vt[bh][64][T].
// Output in-place over q section. exp2-softmax, no max subtraction.
// ---------------------------------------------------------------------------
__global__ __launch_bounds__(256)
void attn_mfma(unsigned short* __restrict__ qkv,
               const unsigned short* __restrict__ vt) {
    __shared__ __align__(16) unsigned short Ks[2][64][80];   // [buf][key][d]
    __shared__ __align__(16) unsigned short Vs[2][64][80];   // [buf][d][key]
    __shared__ __align__(16) unsigned short Pb[4][16][72];   // per-wave [qr][key]

    int bh = blockIdx.x;
    int b = bh >> 4, h = bh & 15;
    int qb = (T_ / 64 - 1) - blockIdx.y;     // reversed: big blocks first
    int tid = threadIdx.x;
    int wave = tid >> 6;
    int lane = tid & 63;
    int m16 = lane & 15, quad = lane >> 4;

    const size_t rs = 2 * C_;
    unsigned short* base = qkv + (size_t)b * T_ * rs + h * 64;
    const unsigned short* kb0 = base + C_;
    const unsigned short* vtb = vt + (size_t)bh * 64 * T_;

    int qrow = qb * 64 + wave * 16 + m16;
    const unsigned short* qp = base + (size_t)qrow * rs;
    bf16x8 qf0 = *(const bf16x8*)(qp + quad * 8);
    bf16x8 qf1 = *(const bf16x8*)(qp + 32 + quad * 8);

    f32x4 o[4];
    #pragma unroll
    for (int dt = 0; dt < 4; ++dt) o[dt] = (f32x4){0.f, 0.f, 0.f, 0.f};
    float lrow[4] = {0.f, 0.f, 0.f, 0.f};

    int qg0 = qb * 64 + wave * 16 + quad * 4;
    int ntiles = qb + 1;

    int kkey = tid >> 3, kdc = (tid & 7) << 3;
    int vd   = tid >> 3, vkc = (tid & 7) << 3;

    uint4 ra  = *(const uint4*)(kb0 + (size_t)kkey * rs + kdc);
    uint4 rb  = *(const uint4*)(kb0 + (size_t)(kkey + 32) * rs + kdc);
    uint4 rva = *(const uint4*)(vtb + (size_t)vd * T_ + vkc);
    uint4 rvb = *(const uint4*)(vtb + (size_t)(vd + 32) * T_ + vkc);
    *(uint4*)&Ks[0][kkey][kdc]      = ra;
    *(uint4*)&Ks[0][kkey + 32][kdc] = rb;
    *(uint4*)&Vs[0][vd][vkc]        = rva;
    *(uint4*)&Vs[0][vd + 32][vkc]   = rvb;
    if (ntiles > 1) {
        const unsigned short* kn = kb0 + (size_t)64 * rs;
        ra  = *(const uint4*)(kn + (size_t)kkey * rs + kdc);
        rb  = *(const uint4*)(kn + (size_t)(kkey + 32) * rs + kdc);
        rva = *(const uint4*)(vtb + (size_t)vd * T_ + 64 + vkc);
        rvb = *(const uint4*)(vtb + (size_t)(vd + 32) * T_ + 64 + vkc);
    }
    __syncthreads();

    for (int kt = 0; kt < ntiles; ++kt) {
        int cur = kt & 1;

        f32x4 s[4];
        #pragma unroll
        for (int st = 0; st < 4; ++st) {
            f32x4 acc = (f32x4){0.f, 0.f, 0.f, 0.f};
            bf16x8 k0 = *(const bf16x8*)&Ks[cur][st * 16 + m16][quad * 8];
            bf16x8 k1 = *(const bf16x8*)&Ks[cur][st * 16 + m16][32 + quad * 8];
            acc = __builtin_amdgcn_mfma_f32_16x16x32_bf16(qf0, k0, acc, 0, 0, 0);
            acc = __builtin_amdgcn_mfma_f32_16x16x32_bf16(qf1, k1, acc, 0, 0, 0);
            s[st] = acc;
        }

        if (kt == qb) {
            #pragma unroll
            for (int st = 0; st < 4; ++st) {
                int kg = kt * 64 + st * 16 + m16;
                #pragma unroll
                for (int r = 0; r < 4; ++r)
                    if (kg > qg0 + r) s[st][r] = -1.0e30f;
            }
        }

        #pragma unroll
        for (int st = 0; st < 4; ++st) {
            #pragma unroll
            for (int r = 0; r < 4; ++r) {
                float p = exp2_fast(s[st][r]);
                lrow[r] += p;
                Pb[wave][quad * 4 + r][st * 16 + m16] = f2bf(p);
            }
        }
        __builtin_amdgcn_sched_barrier(0);

        #pragma unroll
        for (int s2 = 0; s2 < 2; ++s2) {
            bf16x8 pa = *(const bf16x8*)&Pb[wave][m16][s2 * 32 + quad * 8];
            #pragma unroll
            for (int dt = 0; dt < 4; ++dt) {
                bf16x8 vv = *(const bf16x8*)&Vs[cur][dt * 16 + m16][s2 * 32 + quad * 8];
                o[dt] = __builtin_amdgcn_mfma_f32_16x16x32_bf16(pa, vv, o[dt], 0, 0, 0);
            }
        }

        if (kt + 1 < ntiles) {
            int nxt = (kt + 1) & 1;
            *(uint4*)&Ks[nxt][kkey][kdc]      = ra;
            *(uint4*)&Ks[nxt][kkey + 32][kdc] = rb;
            *(uint4*)&Vs[nxt][vd][vkc]        = rva;
            *(uint4*)&Vs[nxt][vd + 32][vkc]   = rvb;
            if (kt + 2 < ntiles) {
                const unsigned short* kn = kb0 + (size_t)((kt + 2) * 64) * rs;
                ra  = *(const uint4*)(kn + (size_t)kkey * rs + kdc);
                rb  = *(const uint4*)(kn + (size_t)(kkey + 32) * rs + kdc);
                rva = *(const uint4*)(vtb + (size_t)vd * T_ + (kt + 2) * 64 + vkc);
                rvb = *(const uint4*)(vtb + (size_t)(vd + 32) * T_ + (kt + 2) * 64 + vkc);
            }
        }
        __syncthreads();
    }

    float lf[4];
    #pragma unroll
    for (int r = 0; r < 4; ++r) lf[r] = lrow[r];
    #pragma unroll
    for (int off = 1; off <= 8; off <<= 1)
        #pragma unroll
        for (int r = 0; r < 4; ++r)
            lf[r] += __shfl_xor(lf[r], off);

    #pragma unroll
    for (int r = 0; r < 4; ++r) {
        float inv = 1.0f / lf[r];
        unsigned short* op = base + (size_t)(qg0 + r) * rs;
        #pragma unroll
        for (int dt = 0; dt < 4; ++dt)
            op[dt * 16 + m16] = f2bf(o[dt][r] * inv);
    }
}

// ---------------------------------------------------------------------------
extern "C" void kernel_launch(void* const* d_in, const int* in_sizes, int n_in,
                              void* d_out, int out_size, void* d_ws, size_t ws_size,
                              hipStream_t stream) {
    const float* x      = (const float*)d_in[0];
    const float* w_attn = (const float*)d_in[1];
    const float* b_attn = (const float*)d_in[2];
    const float* w_proj = (const float*)d_in[3];
    const float* b_proj = (const float*)d_in[4];
    float* out = (float*)d_out;

    unsigned short* ws = (unsigned short*)d_ws;
    unsigned short* xb       = ws;                               // [B*T][C]
    unsigned short* w_attn_t = xb + (size_t)B_ * T_ * C_;        // [3C][C]
    unsigned short* w_proj_t = w_attn_t + (size_t)3 * C_ * C_;   // [C][C]
    unsigned short* qkv      = w_proj_t + (size_t)C_ * C_;       // [bstep*T][2C]

    const size_t fixed_hw = (size_t)B_ * T_ * C_ + 4 * (size_t)C_ * C_;
    const size_t per_b_hw = (size_t)T_ * 2 * C_ + (size_t)H_ * 64 * T_; // qk + vt
    int bstep = (ws_size >= (fixed_hw + (size_t)B_ * per_b_hw) * sizeof(unsigned short))
                ? B_ : 1;

    int nx = B_ * T_ * C_;
    convert_f32_bf16<<<nx / 2048, 256, 0, stream>>>(x, xb, nx);
    transpose_f32_bf16<<<dim3(3 * C_ / 32, C_ / 32), dim3(32, 8), 0, stream>>>(
        w_attn, w_attn_t, C_, 3 * C_);
    transpose_f32_bf16<<<dim3(C_ / 32, C_ / 32), dim3(32, 8), 0, stream>>>(
        w_proj, w_proj_t, C_, C_);

    // q pre-scale: (1/sqrt(D)) * log2(e)  -> softmax via exp2, no max-sub
    const float QSCALE = 0.125f * 1.44269504088896341f;

    for (int b0 = 0; b0 < B_; b0 += bstep) {
        int M = bstep * T_;
        const unsigned short* xbb = xb + (size_t)b0 * T_ * C_;
        unsigned short* vt = qkv + (size_t)bstep * T_ * 2 * C_;  // [bstep*H][64][T]

        gemm_qkv<<<dim3(3 * C_ / BN, M / BM), 512, 0, stream>>>(
            xbb, w_attn_t, b_attn, qkv, vt, M, QSCALE);

        attn_mfma<<<dim3(bstep * H_, T_ / 64), 256, 0, stream>>>(qkv, vt);

        gemm_out<<<dim3(C_ / BN, M / BM), 512, 0, stream>>>(
            qkv, w_proj_t, b_proj, out + (size_t)b0 * T_ * C_, M);
    }
}

// Round 4
// 258.111 us; speedup vs baseline: 1.0363x; 1.0293x over previous
//
#include <hip/hip_runtime.h>
#include <hip/hip_bf16.h>
#include <cstdint>

#define B_ 4
#define T_ 2048
#define C_ 1024
#define H_ 16
#define D_ 64

// GEMM tile geometry (both GEMMs): 128x128, BK=64, 4 waves (2M x 2N), 64x64/wave
// LDS = 2 buffers x (A 16 KiB + B 16 KiB) = 64 KiB -> 2 blocks/CU resident.
#define BM 128
#define BN 128
#define BK 64
#define NT (C_ / BK)   // 16

typedef __bf16 bf16x8 __attribute__((ext_vector_type(8)));
typedef float f32x4 __attribute__((ext_vector_type(4)));

static __device__ __forceinline__ unsigned short f2bf(float f) {
    unsigned int i = __float_as_uint(f);
    unsigned int r = (i + 0x7FFFu + ((i >> 16) & 1u)) >> 16;
    return (unsigned short)r;
}
static __device__ __forceinline__ float exp2_fast(float x) {
    float r;
    asm("v_exp_f32 %0, %1" : "=v"(r) : "v"(x));
    return r;
}

// async global->LDS, 16B per lane (HW: LDS dest = wave-uniform base + lane*16)
static __device__ __forceinline__ void gl_lds16(const unsigned short* g,
                                                unsigned short* l) {
    __builtin_amdgcn_global_load_lds(
        (const __attribute__((address_space(1))) unsigned int*)g,
        (__attribute__((address_space(3))) unsigned int*)l, 16, 0, 0);
}

// ---------------------------------------------------------------------------
// One-time prep: fp32 -> bf16 convert (n % 8 == 0)
// ---------------------------------------------------------------------------
__global__ __launch_bounds__(256)
void convert_f32_bf16(const float* __restrict__ in,
                      unsigned short* __restrict__ out, int n) {
    int i = (blockIdx.x * 256 + threadIdx.x) * 8;
    if (i < n) {
        float4 a = *(const float4*)(in + i);
        float4 b = *(const float4*)(in + i + 4);
        ushort4 s0 = {f2bf(a.x), f2bf(a.y), f2bf(a.z), f2bf(a.w)};
        ushort4 s1 = {f2bf(b.x), f2bf(b.y), f2bf(b.z), f2bf(b.w)};
        *(ushort4*)(out + i) = s0;
        *(ushort4*)(out + i + 4) = s1;
    }
}

// ---------------------------------------------------------------------------
// One-time prep: fp32 [R][Cc] -> bf16 [Cc][R] transpose
// ---------------------------------------------------------------------------
__global__ void transpose_f32_bf16(const float* __restrict__ in,
                                   unsigned short* __restrict__ out,
                                   int R, int Cc) {
    __shared__ unsigned short tile[32][33];
    int c0 = blockIdx.x * 32;
    int r0 = blockIdx.y * 32;
    int tx = threadIdx.x, ty = threadIdx.y;
    #pragma unroll
    for (int i = ty; i < 32; i += 8)
        tile[i][tx] = f2bf(in[(size_t)(r0 + i) * Cc + c0 + tx]);
    __syncthreads();
    #pragma unroll
    for (int i = ty; i < 32; i += 8)
        out[(size_t)(c0 + i) * R + r0 + tx] = tile[tx][i];
}

// ===========================================================================
// 128x128 GEMM core (shared by both GEMMs via macro):
//  - 2-buffer LDS (64 KiB) -> 2 independent blocks/CU (m114 cross-block
//    overlap is the latency-hiding mechanism; no intra-block phase lockstep)
//  - stage tile t+1 BEFORE computing tile t; single vmcnt(0) AFTER the MFMA
//    cluster (loads get a full K-tile to land), raw s_barrier (no compiler
//    pre-compute drain)
//  - XOR chunk swizzle both-sides (pre-swizzled global source at staging,
//    swizzled chunk on ds_read) -> conflict-free ds_read_b128
// LDS layout (u16): A(buf) at buf*8192, B(buf) at 16384+buf*8192,
//   row-major [128][64]; phys chunk p holds logical chunk p^(row&7).
// ===========================================================================
#define GEMM128_CORE(APTR, ASTRIDE, BTPTR)                                    \
    int tid = threadIdx.x;                                                    \
    int nwg = gridDim.x * gridDim.y;                                          \
    int flat = blockIdx.y * gridDim.x + blockIdx.x;                           \
    int swz = (flat & 7) * (nwg >> 3) + (flat >> 3);                          \
    int bx = swz % gridDim.x;                                                 \
    int by = swz / gridDim.x;                                                 \
    int row0 = by * BM;                                                       \
    int col0 = bx * BN;                                                       \
    int wave = tid >> 6, lane = tid & 63;                                     \
    int wm = wave >> 1, wn = wave & 1;                                        \
    int m16 = lane & 15, quad = lane >> 4;                                    \
    int srow = tid >> 3;                                                      \
    int scs = ((tid & 7) ^ (srow & 7)) * 8;                                   \
    const unsigned short* aps = (APTR) + (size_t)(row0 + srow) * (ASTRIDE)    \
                                + scs;                                        \
    const unsigned short* bps = (BTPTR) + (size_t)(col0 + srow) * C_ + scs;   \
    f32x4 acc[4][4];                                                          \
    _Pragma("unroll")                                                         \
    for (int i = 0; i < 4; ++i)                                               \
    _Pragma("unroll")                                                         \
    for (int j = 0; j < 4; ++j)                                               \
        acc[i][j] = (f32x4){0.f, 0.f, 0.f, 0.f};                              \
    auto STAGE = [&](int t, int buf) {                                        \
        int koff = t * BK;                                                    \
        unsigned short* ad = smem + buf * 8192 + tid * 8;                     \
        unsigned short* bd = smem + 16384 + buf * 8192 + tid * 8;             \
        _Pragma("unroll")                                                     \
        for (int l = 0; l < 4; ++l) {                                         \
            gl_lds16(aps + (size_t)(l * 32) * (ASTRIDE) + koff, ad + l * 2048);\
            gl_lds16(bps + (size_t)(l * 32) * C_ + koff, bd + l * 2048);      \
        }                                                                     \
    };                                                                        \
    int rbA = wm * 64 + m16;                                                  \
    int rbB = wn * 64 + m16;                                                  \
    int pc0 = ((0 + quad) ^ (m16 & 7)) * 8;                                   \
    int pc1 = ((4 + quad) ^ (m16 & 7)) * 8;                                   \
    STAGE(0, 0);                                                              \
    asm volatile("s_waitcnt vmcnt(0)" ::: "memory");                          \
    __builtin_amdgcn_s_barrier();                                             \
    for (int t = 0; t < NT; ++t) {                                            \
        int buf = t & 1;                                                      \
        if (t + 1 < NT) STAGE(t + 1, buf ^ 1);                                \
        const unsigned short* Abuf = smem + buf * 8192;                       \
        const unsigned short* Bbuf = smem + 16384 + buf * 8192;               \
        bf16x8 a0[4], a1[4], b0[4], b1[4];                                    \
        _Pragma("unroll")                                                     \
        for (int i = 0; i < 4; ++i) {                                         \
            a0[i] = *(const bf16x8*)(Abuf + (rbA + i * 16) * 64 + pc0);       \
            a1[i] = *(const bf16x8*)(Abuf + (rbA + i * 16) * 64 + pc1);       \
        }                                                                     \
        _Pragma("unroll")                                                     \
        for (int j = 0; j < 4; ++j) {                                         \
            b0[j] = *(const bf16x8*)(Bbuf + (rbB + j * 16) * 64 + pc0);       \
            b1[j] = *(const bf16x8*)(Bbuf + (rbB + j * 16) * 64 + pc1);       \
        }                                                                     \
        __builtin_amdgcn_s_setprio(1);                                        \
        _Pragma("unroll")                                                     \
        for (int i = 0; i < 4; ++i)                                           \
        _Pragma("unroll")                                                     \
        for (int j = 0; j < 4; ++j) {                                         \
            acc[i][j] = __builtin_amdgcn_mfma_f32_16x16x32_bf16(              \
                a0[i], b0[j], acc[i][j], 0, 0, 0);                            \
            acc[i][j] = __builtin_amdgcn_mfma_f32_16x16x32_bf16(              \
                a1[i], b1[j], acc[i][j], 0, 0, 0);                            \
        }                                                                     \
        __builtin_amdgcn_s_setprio(0);                                        \
        asm volatile("s_waitcnt vmcnt(0)" ::: "memory");                      \
        __builtin_amdgcn_s_barrier();                                        \
    }                                                                         \
    __syncthreads();

// ---------------------------------------------------------------------------
// GEMM1 (fused): [M x 3C] = A[M][C] @ w_attn_t[3C][C]^T + b_attn
//  - q cols (<C):    *qscale, bf16 -> qkv[row][2C] at col
//  - k cols (C..2C): bf16 -> qkv[row][2C] at col
//  - v cols (>=2C):  bf16 -> vt[(b*H+h)][d][T] (transposed store)
// ---------------------------------------------------------------------------
__global__ __launch_bounds__(256, 2)
void gemm_qkv(const unsigned short* __restrict__ A,
              const unsigned short* __restrict__ Bt,
              const float* __restrict__ bias,
              unsigned short* __restrict__ qkv,
              unsigned short* __restrict__ vt,
              int M, float qscale) {
    __shared__ __align__(16) unsigned short smem[32768];   // 64 KiB
    GEMM128_CORE(A, C_, Bt)

    // ---- epilogue (per-wave 64x64 tile via wave-private LDS roundtrip) ----
    float bv[4];
    #pragma unroll
    for (int j = 0; j < 4; ++j)
        bv[j] = bias[col0 + wn * 64 + j * 16 + m16];

    unsigned short* wbuf = smem + wave * 2048;   // 4 KiB per wave, 4 waves
    bool isV = (col0 >= 2 * C_);
    float sc = (col0 < C_) ? qscale : 1.0f;
    int b_loc = row0 >> 11;            // batch index (T=2048, 128 | T)
    int trow0 = (row0 & 2047) + wm * 64;
    int head = isV ? ((col0 - 2 * C_ + wn * 64) >> 6) : 0;
    unsigned short* vtb = vt + (size_t)((b_loc * H_ + head) * 64) * T_;

    #pragma unroll
    for (int sub = 0; sub < 4; ++sub) {
        int i0 = (sub >> 1) << 1;      // 0,0,2,2
        int j0 = (sub & 1) << 1;       // 0,2,0,2
        #pragma unroll
        for (int jj = 0; jj < 2; ++jj) {
            #pragma unroll
            for (int ii = 0; ii < 2; ++ii) {
                #pragma unroll
                for (int rr = 0; rr < 4; ++rr) {
                    int rl = ii * 16 + quad * 4 + rr;
                    int cl = jj * 16 + m16;
                    unsigned short hv =
                        f2bf((acc[i0 + ii][j0 + jj][rr] + bv[j0 + jj]) * sc);
                    if (!isV) wbuf[rl * 40 + cl] = hv;      // [row][col]
                    else      wbuf[cl * 40 + rl] = hv;      // [col][row]
                }
            }
        }
        __builtin_amdgcn_sched_barrier(0);
        if (!isV) {
            #pragma unroll
            for (int it = 0; it < 4; ++it) {
                int rl = it * 8 + (lane >> 3);
                int cc = (lane & 7) << 2;
                uint2 v2 = *(const uint2*)&wbuf[rl * 40 + cc];
                int rowg = row0 + wm * 64 + i0 * 16 + rl;
                int colg = col0 + wn * 64 + j0 * 16 + cc;
                *(uint2*)&qkv[(size_t)rowg * (2 * C_) + colg] = v2;
            }
        } else {
            #pragma unroll
            for (int it = 0; it < 4; ++it) {
                int dsub = it * 8 + (lane >> 3);
                int tc = (lane & 7) << 2;
                uint2 v2 = *(const uint2*)&wbuf[dsub * 40 + tc];
                int d = j0 * 16 + dsub;
                int tg = trow0 + i0 * 16 + tc;
                *(uint2*)&vtb[(size_t)d * T_ + tg] = v2;
            }
        }
        __builtin_amdgcn_sched_barrier(0);
    }
}

// ---------------------------------------------------------------------------
// GEMM2: out[M][C] (fp32) = A[M][K=C] (bf16, row stride 2C) @ w_proj_t^T + b
// Direct fp32 stores (16 lanes x 4 B = full 64-B lines).
// ---------------------------------------------------------------------------
__global__ __launch_bounds__(256, 2)
void gemm_out(const unsigned short* __restrict__ A,
              const unsigned short* __restrict__ Bt,
              const float* __restrict__ bias,
              float* __restrict__ Cmat,
              int M) {
    const int N = C_;
    __shared__ __align__(16) unsigned short smem[32768];
    GEMM128_CORE(A, (2 * C_), Bt)

    #pragma unroll
    for (int j = 0; j < 4; ++j) {
        int col = col0 + wn * 64 + j * 16 + m16;
        float bvv = bias[col];
        #pragma unroll
        for (int i = 0; i < 4; ++i) {
            int row = row0 + wm * 64 + i * 16 + quad * 4;
            #pragma unroll
            for (int rr = 0; rr < 4; ++rr)
                Cmat[(size_t)(row + rr) * N + col] = acc[i][j][rr] + bvv;
        }
    }
}

// ---------------------------------------------------------------------------
// MFMA causal flash attention over qk[row][2C] (q|k), V from vt[bh][64][T].
// Output in-place over q section. exp2-softmax, no max subtraction.
// K/V LDS tiles are [64][64] with XOR chunk swizzle (write+read side) ->
// conflict-free ds_read_b128 (was 4-way at stride-80).
// ---------------------------------------------------------------------------
__global__ __launch_bounds__(256)
void attn_mfma(unsigned short* __restrict__ qkv,
               const unsigned short* __restrict__ vt) {
    __shared__ __align__(16) unsigned short Ks[2][64][64];   // [buf][key][d]
    __shared__ __align__(16) unsigned short Vs[2][64][64];   // [buf][d][key]
    __shared__ __align__(16) unsigned short Pb[4][16][72];   // per-wave [qr][key]

    int bh = blockIdx.x;
    int b = bh >> 4, h = bh & 15;
    int qb = (T_ / 64 - 1) - blockIdx.y;     // reversed: big blocks first
    int tid = threadIdx.x;
    int wave = tid >> 6;
    int lane = tid & 63;
    int m16 = lane & 15, quad = lane >> 4;

    const size_t rs = 2 * C_;
    unsigned short* base = qkv + (size_t)b * T_ * rs + h * 64;
    const unsigned short* kb0 = base + C_;
    const unsigned short* vtb = vt + (size_t)bh * 64 * T_;

    int qrow = qb * 64 + wave * 16 + m16;
    const unsigned short* qp = base + (size_t)qrow * rs;
    bf16x8 qf0 = *(const bf16x8*)(qp + quad * 8);
    bf16x8 qf1 = *(const bf16x8*)(qp + 32 + quad * 8);

    f32x4 o[4];
    #pragma unroll
    for (int dt = 0; dt < 4; ++dt) o[dt] = (f32x4){0.f, 0.f, 0.f, 0.f};
    float lrow[4] = {0.f, 0.f, 0.f, 0.f};

    int qg0 = qb * 64 + wave * 16 + quad * 4;
    int ntiles = qb + 1;

    int kkey = tid >> 3, kdc = (tid & 7) << 3;
    int kswz = (((tid & 7) ^ (kkey & 7)) << 3);   // phys chunk byte-offset/2
    int vd = kkey, vswz = kswz;

    // read-side swizzled chunk offsets (row&7 == m16&7 for all our rows)
    int kpc0 = ((0 + quad) ^ (m16 & 7)) << 3;
    int kpc1 = ((4 + quad) ^ (m16 & 7)) << 3;

    uint4 ra  = *(const uint4*)(kb0 + (size_t)kkey * rs + kdc);
    uint4 rb  = *(const uint4*)(kb0 + (size_t)(kkey + 32) * rs + kdc);
    uint4 rva = *(const uint4*)(vtb + (size_t)vd * T_ + kdc);
    uint4 rvb = *(const uint4*)(vtb + (size_t)(vd + 32) * T_ + kdc);
    *(uint4*)&Ks[0][kkey][kswz]      = ra;
    *(uint4*)&Ks[0][kkey + 32][kswz] = rb;
    *(uint4*)&Vs[0][vd][vswz]        = rva;
    *(uint4*)&Vs[0][vd + 32][vswz]   = rvb;
    if (ntiles > 1) {
        const unsigned short* kn = kb0 + (size_t)64 * rs;
        ra  = *(const uint4*)(kn + (size_t)kkey * rs + kdc);
        rb  = *(const uint4*)(kn + (size_t)(kkey + 32) * rs + kdc);
        rva = *(const uint4*)(vtb + (size_t)vd * T_ + 64 + kdc);
        rvb = *(const uint4*)(vtb + (size_t)(vd + 32) * T_ + 64 + kdc);
    }
    __syncthreads();

    for (int kt = 0; kt < ntiles; ++kt) {
        int cur = kt & 1;

        f32x4 s[4];
        #pragma unroll
        for (int st = 0; st < 4; ++st) {
            f32x4 acc = (f32x4){0.f, 0.f, 0.f, 0.f};
            bf16x8 k0 = *(const bf16x8*)&Ks[cur][st * 16 + m16][kpc0];
            bf16x8 k1 = *(const bf16x8*)&Ks[cur][st * 16 + m16][kpc1];
            acc = __builtin_amdgcn_mfma_f32_16x16x32_bf16(qf0, k0, acc, 0, 0, 0);
            acc = __builtin_amdgcn_mfma_f32_16x16x32_bf16(qf1, k1, acc, 0, 0, 0);
            s[st] = acc;
        }

        if (kt == qb) {
            #pragma unroll
            for (int st = 0; st < 4; ++st) {
                int kg = kt * 64 + st * 16 + m16;
                #pragma unroll
                for (int r = 0; r < 4; ++r)
                    if (kg > qg0 + r) s[st][r] = -1.0e30f;
            }
        }

        #pragma unroll
        for (int st = 0; st < 4; ++st) {
            #pragma unroll
            for (int r = 0; r < 4; ++r) {
                float p = exp2_fast(s[st][r]);
                lrow[r] += p;
                Pb[wave][quad * 4 + r][st * 16 + m16] = f2bf(p);
            }
        }
        __builtin_amdgcn_sched_barrier(0);

        #pragma unroll
        for (int s2 = 0; s2 < 2; ++s2) {
            bf16x8 pa = *(const bf16x8*)&Pb[wave][m16][s2 * 32 + quad * 8];
            int vpc = ((s2 * 4 + quad) ^ (m16 & 7)) << 3;
            #pragma unroll
            for (int dt = 0; dt < 4; ++dt) {
                bf16x8 vv = *(const bf16x8*)&Vs[cur][dt * 16 + m16][vpc];
                o[dt] = __builtin_amdgcn_mfma_f32_16x16x32_bf16(pa, vv, o[dt], 0, 0, 0);
            }
        }

        if (kt + 1 < ntiles) {
            int nxt = (kt + 1) & 1;
            *(uint4*)&Ks[nxt][kkey][kswz]      = ra;
            *(uint4*)&Ks[nxt][kkey + 32][kswz] = rb;
            *(uint4*)&Vs[nxt][vd][vswz]        = rva;
            *(uint4*)&Vs[nxt][vd + 32][vswz]   = rvb;
            if (kt + 2 < ntiles) {
                const unsigned short* kn = kb0 + (size_t)((kt + 2) * 64) * rs;
                ra  = *(const uint4*)(kn + (size_t)kkey * rs + kdc);
                rb  = *(const uint4*)(kn + (size_t)(kkey + 32) * rs + kdc);
                rva = *(const uint4*)(vtb + (size_t)vd * T_ + (kt + 2) * 64 + kdc);
                rvb = *(const uint4*)(vtb + (size_t)(vd + 32) * T_ + (kt + 2) * 64 + kdc);
            }
        }
        __syncthreads();
    }

    float lf[4];
    #pragma unroll
    for (int r = 0; r < 4; ++r) lf[r] = lrow[r];
    #pragma unroll
    for (int off = 1; off <= 8; off <<= 1)
        #pragma unroll
        for (int r = 0; r < 4; ++r)
            lf[r] += __shfl_xor(lf[r], off);

    #pragma unroll
    for (int r = 0; r < 4; ++r) {
        float inv = 1.0f / lf[r];
        unsigned short* op = base + (size_t)(qg0 + r) * rs;
        #pragma unroll
        for (int dt = 0; dt < 4; ++dt)
            op[dt * 16 + m16] = f2bf(o[dt][r] * inv);
    }
}

// ---------------------------------------------------------------------------
extern "C" void kernel_launch(void* const* d_in, const int* in_sizes, int n_in,
                              void* d_out, int out_size, void* d_ws, size_t ws_size,
                              hipStream_t stream) {
    const float* x      = (const float*)d_in[0];
    const float* w_attn = (const float*)d_in[1];
    const float* b_attn = (const float*)d_in[2];
    const float* w_proj = (const float*)d_in[3];
    const float* b_proj = (const float*)d_in[4];
    float* out = (float*)d_out;

    unsigned short* ws = (unsigned short*)d_ws;
    unsigned short* xb       = ws;                               // [B*T][C]
    unsigned short* w_attn_t = xb + (size_t)B_ * T_ * C_;        // [3C][C]
    unsigned short* w_proj_t = w_attn_t + (size_t)3 * C_ * C_;   // [C][C]
    unsigned short* qkv      = w_proj_t + (size_t)C_ * C_;       // [bstep*T][2C]

    const size_t fixed_hw = (size_t)B_ * T_ * C_ + 4 * (size_t)C_ * C_;
    const size_t per_b_hw = (size_t)T_ * 2 * C_ + (size_t)H_ * 64 * T_; // qk + vt
    int bstep = (ws_size >= (fixed_hw + (size_t)B_ * per_b_hw) * sizeof(unsigned short))
                ? B_ : 1;

    int nx = B_ * T_ * C_;
    convert_f32_bf16<<<nx / 2048, 256, 0, stream>>>(x, xb, nx);
    transpose_f32_bf16<<<dim3(3 * C_ / 32, C_ / 32), dim3(32, 8), 0, stream>>>(
        w_attn, w_attn_t, C_, 3 * C_);
    transpose_f32_bf16<<<dim3(C_ / 32, C_ / 32), dim3(32, 8), 0, stream>>>(
        w_proj, w_proj_t, C_, C_);

    // q pre-scale: (1/sqrt(D)) * log2(e)  -> softmax via exp2, no max-sub
    const float QSCALE = 0.125f * 1.44269504088896341f;

    for (int b0 = 0; b0 < B_; b0 += bstep) {
        int M = bstep * T_;
        const unsigned short* xbb = xb + (size_t)b0 * T_ * C_;
        unsigned short* vt = qkv + (size_t)bstep * T_ * 2 * C_;  // [bstep*H][64][T]

        gemm_qkv<<<dim3(3 * C_ / BN, M / BM), 256, 0, stream>>>(
            xbb, w_attn_t, b_attn, qkv, vt, M, QSCALE);

        attn_mfma<<<dim3(bstep * H_, T_ / 64), 256, 0, stream>>>(qkv, vt);

        gemm_out<<<dim3(C_ / BN, M / BM), 256, 0, stream>>>(
            qkv, w_proj_t, b_proj, out + (size_t)b0 * T_ * C_, M);
    }
}

// Round 6
// 256.472 us; speedup vs baseline: 1.0430x; 1.0064x over previous
//
#include <hip/hip_runtime.h>
#include <hip/hip_bf16.h>
#include <cstdint>

#define B_ 4
#define T_ 2048
#define C_ 1024
#define H_ 16
#define D_ 64

// GEMM tile geometry (both GEMMs): 128x128, BK=64, 4 waves (2M x 2N), 64x64/wave
// LDS = 2 buffers x (A 16 KiB + B 16 KiB) = 64 KiB -> 2 blocks/CU resident.
#define BM 128
#define BN 128
#define BK 64
#define NT (C_ / BK)   // 16

typedef __bf16 bf16x8 __attribute__((ext_vector_type(8)));
typedef float f32x4 __attribute__((ext_vector_type(4)));

static __device__ __forceinline__ unsigned short f2bf(float f) {
    unsigned int i = __float_as_uint(f);
    unsigned int r = (i + 0x7FFFu + ((i >> 16) & 1u)) >> 16;
    return (unsigned short)r;
}
static __device__ __forceinline__ float exp2_fast(float x) {
    float r;
    asm("v_exp_f32 %0, %1" : "=v"(r) : "v"(x));
    return r;
}

// async global->LDS, 16B per lane (HW: LDS dest = wave-uniform base + lane*16)
static __device__ __forceinline__ void gl_lds16(const unsigned short* g,
                                                unsigned short* l) {
    __builtin_amdgcn_global_load_lds(
        (const __attribute__((address_space(1))) unsigned int*)g,
        (__attribute__((address_space(3))) unsigned int*)l, 16, 0, 0);
}

// ---------------------------------------------------------------------------
// One-time prep: fp32 -> bf16 convert (n % 8 == 0)
// ---------------------------------------------------------------------------
__global__ __launch_bounds__(256)
void convert_f32_bf16(const float* __restrict__ in,
                      unsigned short* __restrict__ out, int n) {
    int i = (blockIdx.x * 256 + threadIdx.x) * 8;
    if (i < n) {
        float4 a = *(const float4*)(in + i);
        float4 b = *(const float4*)(in + i + 4);
        ushort4 s0 = {f2bf(a.x), f2bf(a.y), f2bf(a.z), f2bf(a.w)};
        ushort4 s1 = {f2bf(b.x), f2bf(b.y), f2bf(b.z), f2bf(b.w)};
        *(ushort4*)(out + i) = s0;
        *(ushort4*)(out + i + 4) = s1;
    }
}

// ---------------------------------------------------------------------------
// One-time prep: fp32 [R][Cc] -> bf16 [Cc][R] transpose
// ---------------------------------------------------------------------------
__global__ void transpose_f32_bf16(const float* __restrict__ in,
                                   unsigned short* __restrict__ out,
                                   int R, int Cc) {
    __shared__ unsigned short tile[32][33];
    int c0 = blockIdx.x * 32;
    int r0 = blockIdx.y * 32;
    int tx = threadIdx.x, ty = threadIdx.y;
    #pragma unroll
    for (int i = ty; i < 32; i += 8)
        tile[i][tx] = f2bf(in[(size_t)(r0 + i) * Cc + c0 + tx]);
    __syncthreads();
    #pragma unroll
    for (int i = ty; i < 32; i += 8)
        out[(size_t)(c0 + i) * R + r0 + tx] = tile[tx][i];
}

// ===========================================================================
// 128x128 GEMM core (shared by both GEMMs via macro):
//  - 2-buffer LDS (64 KiB) -> 2 independent blocks/CU (m114 cross-block
//    overlap is the latency-hiding mechanism; no intra-block phase lockstep)
//  - stage tile t+1 BEFORE computing tile t; single vmcnt(0) AFTER the MFMA
//    cluster (loads get a full K-tile to land), raw s_barrier (no compiler
//    pre-compute drain)
//  - XOR chunk swizzle both-sides (pre-swizzled global source at staging,
//    swizzled chunk on ds_read) -> conflict-free ds_read_b128
// LDS layout (u16): A(buf) at buf*8192, B(buf) at 16384+buf*8192,
//   row-major [128][64]; phys chunk p holds logical chunk p^(row&7).
// ===========================================================================
#define GEMM128_CORE(APTR, ASTRIDE, BTPTR)                                    \
    int tid = threadIdx.x;                                                    \
    int nwg = gridDim.x * gridDim.y;                                          \
    int flat = blockIdx.y * gridDim.x + blockIdx.x;                           \
    int swz = (flat & 7) * (nwg >> 3) + (flat >> 3);                          \
    int bx = swz % gridDim.x;                                                 \
    int by = swz / gridDim.x;                                                 \
    int row0 = by * BM;                                                       \
    int col0 = bx * BN;                                                       \
    int wave = tid >> 6, lane = tid & 63;                                     \
    int wm = wave >> 1, wn = wave & 1;                                        \
    int m16 = lane & 15, quad = lane >> 4;                                    \
    int srow = tid >> 3;                                                      \
    int scs = ((tid & 7) ^ (srow & 7)) * 8;                                   \
    const unsigned short* aps = (APTR) + (size_t)(row0 + srow) * (ASTRIDE)    \
                                + scs;                                        \
    const unsigned short* bps = (BTPTR) + (size_t)(col0 + srow) * C_ + scs;   \
    f32x4 acc[4][4];                                                          \
    _Pragma("unroll")                                                         \
    for (int i = 0; i < 4; ++i)                                               \
    _Pragma("unroll")                                                         \
    for (int j = 0; j < 4; ++j)                                               \
        acc[i][j] = (f32x4){0.f, 0.f, 0.f, 0.f};                              \
    auto STAGE = [&](int t, int buf) {                                        \
        int koff = t * BK;                                                    \
        unsigned short* ad = smem + buf * 8192 + tid * 8;                     \
        unsigned short* bd = smem + 16384 + buf * 8192 + tid * 8;             \
        _Pragma("unroll")                                                     \
        for (int l = 0; l < 4; ++l) {                                         \
            gl_lds16(aps + (size_t)(l * 32) * (ASTRIDE) + koff, ad + l * 2048);\
            gl_lds16(bps + (size_t)(l * 32) * C_ + koff, bd + l * 2048);      \
        }                                                                     \
    };                                                                        \
    int rbA = wm * 64 + m16;                                                  \
    int rbB = wn * 64 + m16;                                                  \
    int pc0 = ((0 + quad) ^ (m16 & 7)) * 8;                                   \
    int pc1 = ((4 + quad) ^ (m16 & 7)) * 8;                                   \
    STAGE(0, 0);                                                              \
    asm volatile("s_waitcnt vmcnt(0)" ::: "memory");                          \
    __builtin_amdgcn_s_barrier();                                             \
    for (int t = 0; t < NT; ++t) {                                            \
        int buf = t & 1;                                                      \
        if (t + 1 < NT) STAGE(t + 1, buf ^ 1);                                \
        const unsigned short* Abuf = smem + buf * 8192;                       \
        const unsigned short* Bbuf = smem + 16384 + buf * 8192;               \
        bf16x8 a0[4], a1[4], b0[4], b1[4];                                    \
        _Pragma("unroll")                                                     \
        for (int i = 0; i < 4; ++i) {                                         \
            a0[i] = *(const bf16x8*)(Abuf + (rbA + i * 16) * 64 + pc0);       \
            a1[i] = *(const bf16x8*)(Abuf + (rbA + i * 16) * 64 + pc1);       \
        }                                                                     \
        _Pragma("unroll")                                                     \
        for (int j = 0; j < 4; ++j) {                                         \
            b0[j] = *(const bf16x8*)(Bbuf + (rbB + j * 16) * 64 + pc0);       \
            b1[j] = *(const bf16x8*)(Bbuf + (rbB + j * 16) * 64 + pc1);       \
        }                                                                     \
        __builtin_amdgcn_s_setprio(1);                                        \
        _Pragma("unroll")                                                     \
        for (int i = 0; i < 4; ++i)                                           \
        _Pragma("unroll")                                                     \
        for (int j = 0; j < 4; ++j) {                                         \
            acc[i][j] = __builtin_amdgcn_mfma_f32_16x16x32_bf16(              \
                a0[i], b0[j], acc[i][j], 0, 0, 0);                            \
            acc[i][j] = __builtin_amdgcn_mfma_f32_16x16x32_bf16(              \
                a1[i], b1[j], acc[i][j], 0, 0, 0);                            \
        }                                                                     \
        __builtin_amdgcn_s_setprio(0);                                        \
        asm volatile("s_waitcnt vmcnt(0)" ::: "memory");                      \
        __builtin_amdgcn_s_barrier();                                        \
    }                                                                         \
    __syncthreads();

// ---------------------------------------------------------------------------
// GEMM1 (fused): [M x 3C] = A[M][C] @ w_attn_t[3C][C]^T + b_attn
//  - q cols (<C):    *qscale, bf16 -> qkv[row][2C] at col
//  - k cols (C..2C): bf16 -> qkv[row][2C] at col
//  - v cols (>=2C):  bf16 -> vt[(b*H+h)][d][T] (transposed store)
// ---------------------------------------------------------------------------
__global__ __launch_bounds__(256, 2)
void gemm_qkv(const unsigned short* __restrict__ A,
              const unsigned short* __restrict__ Bt,
              const float* __restrict__ bias,
              unsigned short* __restrict__ qkv,
              unsigned short* __restrict__ vt,
              int M, float qscale) {
    __shared__ __align__(16) unsigned short smem[32768];   // 64 KiB
    GEMM128_CORE(A, C_, Bt)

    // ---- epilogue (per-wave 64x64 tile via wave-private LDS roundtrip) ----
    float bv[4];
    #pragma unroll
    for (int j = 0; j < 4; ++j)
        bv[j] = bias[col0 + wn * 64 + j * 16 + m16];

    unsigned short* wbuf = smem + wave * 2048;   // 4 KiB per wave, 4 waves
    bool isV = (col0 >= 2 * C_);
    float sc = (col0 < C_) ? qscale : 1.0f;
    int b_loc = row0 >> 11;            // batch index (T=2048, 128 | T)
    int trow0 = (row0 & 2047) + wm * 64;
    int head = isV ? ((col0 - 2 * C_ + wn * 64) >> 6) : 0;
    unsigned short* vtb = vt + (size_t)((b_loc * H_ + head) * 64) * T_;

    #pragma unroll
    for (int sub = 0; sub < 4; ++sub) {
        int i0 = (sub >> 1) << 1;      // 0,0,2,2
        int j0 = (sub & 1) << 1;       // 0,2,0,2
        #pragma unroll
        for (int jj = 0; jj < 2; ++jj) {
            #pragma unroll
            for (int ii = 0; ii < 2; ++ii) {
                #pragma unroll
                for (int rr = 0; rr < 4; ++rr) {
                    int rl = ii * 16 + quad * 4 + rr;
                    int cl = jj * 16 + m16;
                    unsigned short hv =
                        f2bf((acc[i0 + ii][j0 + jj][rr] + bv[j0 + jj]) * sc);
                    if (!isV) wbuf[rl * 40 + cl] = hv;      // [row][col]
                    else      wbuf[cl * 40 + rl] = hv;      // [col][row]
                }
            }
        }
        __builtin_amdgcn_sched_barrier(0);
        if (!isV) {
            #pragma unroll
            for (int it = 0; it < 4; ++it) {
                int rl = it * 8 + (lane >> 3);
                int cc = (lane & 7) << 2;
                uint2 v2 = *(const uint2*)&wbuf[rl * 40 + cc];
                int rowg = row0 + wm * 64 + i0 * 16 + rl;
                int colg = col0 + wn * 64 + j0 * 16 + cc;
                *(uint2*)&qkv[(size_t)rowg * (2 * C_) + colg] = v2;
            }
        } else {
            #pragma unroll
            for (int it = 0; it < 4; ++it) {
                int dsub = it * 8 + (lane >> 3);
                int tc = (lane & 7) << 2;
                uint2 v2 = *(const uint2*)&wbuf[dsub * 40 + tc];
                int d = j0 * 16 + dsub;
                int tg = trow0 + i0 * 16 + tc;
                *(uint2*)&vtb[(size_t)d * T_ + tg] = v2;
            }
        }
        __builtin_amdgcn_sched_barrier(0);
    }
}

// ---------------------------------------------------------------------------
// GEMM2: out[M][C] (fp32) = A[M][K=C] (bf16, row stride 2C) @ w_proj_t^T + b
// Direct fp32 stores (16 lanes x 4 B = full 64-B lines).
// ---------------------------------------------------------------------------
__global__ __launch_bounds__(256, 2)
void gemm_out(const unsigned short* __restrict__ A,
              const unsigned short* __restrict__ Bt,
              const float* __restrict__ bias,
              float* __restrict__ Cmat,
              int M) {
    const int N = C_;
    __shared__ __align__(16) unsigned short smem[32768];
    GEMM128_CORE(A, (2 * C_), Bt)

    #pragma unroll
    for (int j = 0; j < 4; ++j) {
        int col = col0 + wn * 64 + j * 16 + m16;
        float bvv = bias[col];
        #pragma unroll
        for (int i = 0; i < 4; ++i) {
            int row = row0 + wm * 64 + i * 16 + quad * 4;
            #pragma unroll
            for (int rr = 0; rr < 4; ++rr)
                Cmat[(size_t)(row + rr) * N + col] = acc[i][j][rr] + bvv;
        }
    }
}

// ---------------------------------------------------------------------------
// MFMA causal flash attention over qk[row][2C] (q|k), V from vt[bh][64][T].
// Output in-place over q section. exp2-softmax, no max subtraction.
// K/V staged via global_load_lds with pre-swizzled global source (same XOR
// both-sides pattern as the GEMM core); one raw s_barrier + vmcnt(0) per
// K-tile; setprio around MFMA clusters.
// LDS dest check: for wave w lane l, row=w*8+(l>>3), dest = row*128B +
// (l&7)*16B = w*1024B + l*16B  -> linear in lane, gl_lds-compatible.
// ---------------------------------------------------------------------------
__global__ __launch_bounds__(256)
void attn_mfma(unsigned short* __restrict__ qkv,
               const unsigned short* __restrict__ vt) {
    __shared__ __align__(16) unsigned short Ks[2][64][64];   // [buf][key][d]
    __shared__ __align__(16) unsigned short Vs[2][64][64];   // [buf][d][key]
    __shared__ __align__(16) unsigned short Pb[4][16][72];   // per-wave [qr][key]

    int bh = blockIdx.x;
    int b = bh >> 4, h = bh & 15;
    int qb = (T_ / 64 - 1) - blockIdx.y;     // reversed: big blocks first
    int tid = threadIdx.x;
    int wave = tid >> 6;
    int lane = tid & 63;
    int m16 = lane & 15, quad = lane >> 4;

    const size_t rs = 2 * C_;
    unsigned short* base = qkv + (size_t)b * T_ * rs + h * 64;
    const unsigned short* kb0 = base + C_;
    const unsigned short* vtb = vt + (size_t)bh * 64 * T_;

    int qrow = qb * 64 + wave * 16 + m16;
    const unsigned short* qp = base + (size_t)qrow * rs;
    bf16x8 qf0 = *(const bf16x8*)(qp + quad * 8);
    bf16x8 qf1 = *(const bf16x8*)(qp + 32 + quad * 8);

    f32x4 o[4];
    #pragma unroll
    for (int dt = 0; dt < 4; ++dt) o[dt] = (f32x4){0.f, 0.f, 0.f, 0.f};
    float lrow[4] = {0.f, 0.f, 0.f, 0.f};

    int qg0 = qb * 64 + wave * 16 + quad * 4;
    int ntiles = qb + 1;

    // staging geometry: row = tid>>3 (0..31) and row+32; pre-swizzled source
    int srow = tid >> 3;
    int schs = ((tid & 7) ^ (srow & 7)) * 8;   // logical chunk to fetch
    const unsigned short* kps = kb0 + (size_t)srow * rs + schs;
    const unsigned short* vps = vtb + (size_t)srow * T_ + schs;
    unsigned short* kdst = &Ks[0][0][0] + wave * 512;   // +buf*4096 u16
    unsigned short* vdst = &Vs[0][0][0] + wave * 512;

    auto STAGE = [&](int kt, int buf) {
        const unsigned short* ks = kps + (size_t)(kt * 64) * rs;
        const unsigned short* vs = vps + kt * 64;
        unsigned short* kd = kdst + buf * 4096;
        unsigned short* vd = vdst + buf * 4096;
        gl_lds16(ks, kd);
        gl_lds16(ks + (size_t)32 * rs, kd + 2048);
        gl_lds16(vs, vd);
        gl_lds16(vs + (size_t)32 * T_, vd + 2048);
    };

    // read-side swizzled chunk offsets (row&7 == m16&7 for all our rows)
    int kpc0 = ((0 + quad) ^ (m16 & 7)) << 3;
    int kpc1 = ((4 + quad) ^ (m16 & 7)) << 3;

    STAGE(0, 0);
    asm volatile("s_waitcnt vmcnt(0)" ::: "memory");
    __builtin_amdgcn_s_barrier();

    for (int kt = 0; kt < ntiles; ++kt) {
        int cur = kt & 1;
        if (kt + 1 < ntiles) STAGE(kt + 1, cur ^ 1);

        f32x4 s[4];
        #pragma unroll
        for (int st = 0; st < 4; ++st) {
            f32x4 acc = (f32x4){0.f, 0.f, 0.f, 0.f};
            bf16x8 k0 = *(const bf16x8*)&Ks[cur][st * 16 + m16][kpc0];
            bf16x8 k1 = *(const bf16x8*)&Ks[cur][st * 16 + m16][kpc1];
            __builtin_amdgcn_s_setprio(1);
            acc = __builtin_amdgcn_mfma_f32_16x16x32_bf16(qf0, k0, acc, 0, 0, 0);
            acc = __builtin_amdgcn_mfma_f32_16x16x32_bf16(qf1, k1, acc, 0, 0, 0);
            __builtin_amdgcn_s_setprio(0);
            s[st] = acc;
        }

        if (kt == qb) {
            #pragma unroll
            for (int st = 0; st < 4; ++st) {
                int kg = kt * 64 + st * 16 + m16;
                #pragma unroll
                for (int r = 0; r < 4; ++r)
                    if (kg > qg0 + r) s[st][r] = -1.0e30f;
            }
        }

        #pragma unroll
        for (int st = 0; st < 4; ++st) {
            #pragma unroll
            for (int r = 0; r < 4; ++r) {
                float p = exp2_fast(s[st][r]);
                lrow[r] += p;
                Pb[wave][quad * 4 + r][st * 16 + m16] = f2bf(p);
            }
        }
        __builtin_amdgcn_sched_barrier(0);

        #pragma unroll
        for (int s2 = 0; s2 < 2; ++s2) {
            bf16x8 pa = *(const bf16x8*)&Pb[wave][m16][s2 * 32 + quad * 8];
            int vpc = ((s2 * 4 + quad) ^ (m16 & 7)) << 3;
            __builtin_amdgcn_s_setprio(1);
            #pragma unroll
            for (int dt = 0; dt < 4; ++dt) {
                bf16x8 vv = *(const bf16x8*)&Vs[cur][dt * 16 + m16][vpc];
                o[dt] = __builtin_amdgcn_mfma_f32_16x16x32_bf16(pa, vv, o[dt], 0, 0, 0);
            }
            __builtin_amdgcn_s_setprio(0);
        }

        asm volatile("s_waitcnt vmcnt(0)" ::: "memory");
        __builtin_amdgcn_s_barrier();
    }

    float lf[4];
    #pragma unroll
    for (int r = 0; r < 4; ++r) lf[r] = lrow[r];
    #pragma unroll
    for (int off = 1; off <= 8; off <<= 1)
        #pragma unroll
        for (int r = 0; r < 4; ++r)
            lf[r] += __shfl_xor(lf[r], off);

    #pragma unroll
    for (int r = 0; r < 4; ++r) {
        float inv = 1.0f / lf[r];
        unsigned short* op = base + (size_t)(qg0 + r) * rs;
        #pragma unroll
        for (int dt = 0; dt < 4; ++dt)
            op[dt * 16 + m16] = f2bf(o[dt][r] * inv);
    }
}

// ---------------------------------------------------------------------------
extern "C" void kernel_launch(void* const* d_in, const int* in_sizes, int n_in,
                              void* d_out, int out_size, void* d_ws, size_t ws_size,
                              hipStream_t stream) {
    const float* x      = (const float*)d_in[0];
    const float* w_attn = (const float*)d_in[1];
    const float* b_attn = (const float*)d_in[2];
    const float* w_proj = (const float*)d_in[3];
    const float* b_proj = (const float*)d_in[4];
    float* out = (float*)d_out;

    unsigned short* ws = (unsigned short*)d_ws;
    unsigned short* xb       = ws;                               // [B*T][C]
    unsigned short* w_attn_t = xb + (size_t)B_ * T_ * C_;        // [3C][C]
    unsigned short* w_proj_t = w_attn_t + (size_t)3 * C_ * C_;   // [C][C]
    unsigned short* qkv      = w_proj_t + (size_t)C_ * C_;       // [bstep*T][2C]

    const size_t fixed_hw = (size_t)B_ * T_ * C_ + 4 * (size_t)C_ * C_;
    const size_t per_b_hw = (size_t)T_ * 2 * C_ + (size_t)H_ * 64 * T_; // qk + vt
    int bstep = (ws_size >= (fixed_hw + (size_t)B_ * per_b_hw) * sizeof(unsigned short))
                ? B_ : 1;

    int nx = B_ * T_ * C_;
    convert_f32_bf16<<<nx / 2048, 256, 0, stream>>>(x, xb, nx);
    transpose_f32_bf16<<<dim3(3 * C_ / 32, C_ / 32), dim3(32, 8), 0, stream>>>(
        w_attn, w_attn_t, C_, 3 * C_);
    transpose_f32_bf16<<<dim3(C_ / 32, C_ / 32), dim3(32, 8), 0, stream>>>(
        w_proj, w_proj_t, C_, C_);

    // q pre-scale: (1/sqrt(D)) * log2(e)  -> softmax via exp2, no max-sub
    const float QSCALE = 0.125f * 1.44269504088896341f;

    for (int b0 = 0; b0 < B_; b0 += bstep) {
        int M = bstep * T_;
        const unsigned short* xbb = xb + (size_t)b0 * T_ * C_;
        unsigned short* vt = qkv + (size_t)bstep * T_ * 2 * C_;  // [bstep*H][64][T]

        gemm_qkv<<<dim3(3 * C_ / BN, M / BM), 256, 0, stream>>>(
            xbb, w_attn_t, b_attn, qkv, vt, M, QSCALE);

        attn_mfma<<<dim3(bstep * H_, T_ / 64), 256, 0, stream>>>(qkv, vt);

        gemm_out<<<dim3(C_ / BN, M / BM), 256, 0, stream>>>(
            qkv, w_proj_t, b_proj, out + (size_t)b0 * T_ * C_, M);
    }
}

// Round 7
// 249.699 us; speedup vs baseline: 1.0712x; 1.0271x over previous
//
#include <hip/hip_runtime.h>
#include <hip/hip_bf16.h>
#include <cstdint>

#define B_ 4
#define T_ 2048
#define C_ 1024
#define H_ 16
#define D_ 64

// GEMM tile geometry (both GEMMs): 128x128, BK=64, 4 waves (2M x 2N), 64x64/wave
// LDS = 2 buffers x (A 16 KiB + B 16 KiB) = 64 KiB -> 2 blocks/CU resident.
#define BM 128
#define BN 128
#define BK 64
#define NT (C_ / BK)   // 16

typedef __bf16 bf16x8 __attribute__((ext_vector_type(8)));
typedef float f32x4 __attribute__((ext_vector_type(4)));

static __device__ __forceinline__ unsigned short f2bf(float f) {
    unsigned int i = __float_as_uint(f);
    unsigned int r = (i + 0x7FFFu + ((i >> 16) & 1u)) >> 16;
    return (unsigned short)r;
}
// native single-instruction bf16 convert (RTNE on gfx950)
static __device__ __forceinline__ unsigned short f2bf_hw(float f) {
    __bf16 h = (__bf16)f;
    union { __bf16 h; unsigned short u; } cv;
    cv.h = h;
    return cv.u;
}
static __device__ __forceinline__ float exp2_fast(float x) {
    float r;
    asm("v_exp_f32 %0, %1" : "=v"(r) : "v"(x));
    return r;
}

// async global->LDS, 16B per lane (HW: LDS dest = wave-uniform base + lane*16)
static __device__ __forceinline__ void gl_lds16(const unsigned short* g,
                                                unsigned short* l) {
    __builtin_amdgcn_global_load_lds(
        (const __attribute__((address_space(1))) unsigned int*)g,
        (__attribute__((address_space(3))) unsigned int*)l, 16, 0, 0);
}

// ---------------------------------------------------------------------------
// One-time prep: fp32 -> bf16 convert (n % 8 == 0)
// ---------------------------------------------------------------------------
__global__ __launch_bounds__(256)
void convert_f32_bf16(const float* __restrict__ in,
                      unsigned short* __restrict__ out, int n) {
    int i = (blockIdx.x * 256 + threadIdx.x) * 8;
    if (i < n) {
        float4 a = *(const float4*)(in + i);
        float4 b = *(const float4*)(in + i + 4);
        ushort4 s0 = {f2bf(a.x), f2bf(a.y), f2bf(a.z), f2bf(a.w)};
        ushort4 s1 = {f2bf(b.x), f2bf(b.y), f2bf(b.z), f2bf(b.w)};
        *(ushort4*)(out + i) = s0;
        *(ushort4*)(out + i + 4) = s1;
    }
}

// ---------------------------------------------------------------------------
// One-time prep: fp32 [R][Cc] -> bf16 [Cc][R] transpose
// ---------------------------------------------------------------------------
__global__ void transpose_f32_bf16(const float* __restrict__ in,
                                   unsigned short* __restrict__ out,
                                   int R, int Cc) {
    __shared__ unsigned short tile[32][33];
    int c0 = blockIdx.x * 32;
    int r0 = blockIdx.y * 32;
    int tx = threadIdx.x, ty = threadIdx.y;
    #pragma unroll
    for (int i = ty; i < 32; i += 8)
        tile[i][tx] = f2bf(in[(size_t)(r0 + i) * Cc + c0 + tx]);
    __syncthreads();
    #pragma unroll
    for (int i = ty; i < 32; i += 8)
        out[(size_t)(c0 + i) * R + r0 + tx] = tile[tx][i];
}

// ===========================================================================
// 128x128 GEMM core (shared by both GEMMs via macro) — unchanged from R4/R6.
// ===========================================================================
#define GEMM128_CORE(APTR, ASTRIDE, BTPTR)                                    \
    int tid = threadIdx.x;                                                    \
    int nwg = gridDim.x * gridDim.y;                                          \
    int flat = blockIdx.y * gridDim.x + blockIdx.x;                           \
    int swz = (flat & 7) * (nwg >> 3) + (flat >> 3);                          \
    int bx = swz % gridDim.x;                                                 \
    int by = swz / gridDim.x;                                                 \
    int row0 = by * BM;                                                       \
    int col0 = bx * BN;                                                       \
    int wave = tid >> 6, lane = tid & 63;                                     \
    int wm = wave >> 1, wn = wave & 1;                                        \
    int m16 = lane & 15, quad = lane >> 4;                                    \
    int srow = tid >> 3;                                                      \
    int scs = ((tid & 7) ^ (srow & 7)) * 8;                                   \
    const unsigned short* aps = (APTR) + (size_t)(row0 + srow) * (ASTRIDE)    \
                                + scs;                                        \
    const unsigned short* bps = (BTPTR) + (size_t)(col0 + srow) * C_ + scs;   \
    f32x4 acc[4][4];                                                          \
    _Pragma("unroll")                                                         \
    for (int i = 0; i < 4; ++i)                                               \
    _Pragma("unroll")                                                         \
    for (int j = 0; j < 4; ++j)                                               \
        acc[i][j] = (f32x4){0.f, 0.f, 0.f, 0.f};                              \
    auto STAGE = [&](int t, int buf) {                                        \
        int koff = t * BK;                                                    \
        unsigned short* ad = smem + buf * 8192 + tid * 8;                     \
        unsigned short* bd = smem + 16384 + buf * 8192 + tid * 8;             \
        _Pragma("unroll")                                                     \
        for (int l = 0; l < 4; ++l) {                                         \
            gl_lds16(aps + (size_t)(l * 32) * (ASTRIDE) + koff, ad + l * 2048);\
            gl_lds16(bps + (size_t)(l * 32) * C_ + koff, bd + l * 2048);      \
        }                                                                     \
    };                                                                        \
    int rbA = wm * 64 + m16;                                                  \
    int rbB = wn * 64 + m16;                                                  \
    int pc0 = ((0 + quad) ^ (m16 & 7)) * 8;                                   \
    int pc1 = ((4 + quad) ^ (m16 & 7)) * 8;                                   \
    STAGE(0, 0);                                                              \
    asm volatile("s_waitcnt vmcnt(0)" ::: "memory");                          \
    __builtin_amdgcn_s_barrier();                                             \
    for (int t = 0; t < NT; ++t) {                                            \
        int buf = t & 1;                                                      \
        if (t + 1 < NT) STAGE(t + 1, buf ^ 1);                                \
        const unsigned short* Abuf = smem + buf * 8192;                       \
        const unsigned short* Bbuf = smem + 16384 + buf * 8192;               \
        bf16x8 a0[4], a1[4], b0[4], b1[4];                                    \
        _Pragma("unroll")                                                     \
        for (int i = 0; i < 4; ++i) {                                         \
            a0[i] = *(const bf16x8*)(Abuf + (rbA + i * 16) * 64 + pc0);       \
            a1[i] = *(const bf16x8*)(Abuf + (rbA + i * 16) * 64 + pc1);       \
        }                                                                     \
        _Pragma("unroll")                                                     \
        for (int j = 0; j < 4; ++j) {                                         \
            b0[j] = *(const bf16x8*)(Bbuf + (rbB + j * 16) * 64 + pc0);       \
            b1[j] = *(const bf16x8*)(Bbuf + (rbB + j * 16) * 64 + pc1);       \
        }                                                                     \
        __builtin_amdgcn_s_setprio(1);                                        \
        _Pragma("unroll")                                                     \
        for (int i = 0; i < 4; ++i)                                           \
        _Pragma("unroll")                                                     \
        for (int j = 0; j < 4; ++j) {                                         \
            acc[i][j] = __builtin_amdgcn_mfma_f32_16x16x32_bf16(              \
                a0[i], b0[j], acc[i][j], 0, 0, 0);                            \
            acc[i][j] = __builtin_amdgcn_mfma_f32_16x16x32_bf16(              \
                a1[i], b1[j], acc[i][j], 0, 0, 0);                            \
        }                                                                     \
        __builtin_amdgcn_s_setprio(0);                                        \
        asm volatile("s_waitcnt vmcnt(0)" ::: "memory");                      \
        __builtin_amdgcn_s_barrier();                                        \
    }                                                                         \
    __syncthreads();

// ---------------------------------------------------------------------------
// GEMM1 (fused): [M x 3C] = A[M][C] @ w_attn_t[3C][C]^T + b_attn
// ---------------------------------------------------------------------------
__global__ __launch_bounds__(256, 2)
void gemm_qkv(const unsigned short* __restrict__ A,
              const unsigned short* __restrict__ Bt,
              const float* __restrict__ bias,
              unsigned short* __restrict__ qkv,
              unsigned short* __restrict__ vt,
              int M, float qscale) {
    __shared__ __align__(16) unsigned short smem[32768];   // 64 KiB
    GEMM128_CORE(A, C_, Bt)

    // ---- epilogue (per-wave 64x64 tile via wave-private LDS roundtrip) ----
    float bv[4];
    #pragma unroll
    for (int j = 0; j < 4; ++j)
        bv[j] = bias[col0 + wn * 64 + j * 16 + m16];

    unsigned short* wbuf = smem + wave * 2048;   // 4 KiB per wave, 4 waves
    bool isV = (col0 >= 2 * C_);
    float sc = (col0 < C_) ? qscale : 1.0f;
    int b_loc = row0 >> 11;            // batch index (T=2048, 128 | T)
    int trow0 = (row0 & 2047) + wm * 64;
    int head = isV ? ((col0 - 2 * C_ + wn * 64) >> 6) : 0;
    unsigned short* vtb = vt + (size_t)((b_loc * H_ + head) * 64) * T_;

    #pragma unroll
    for (int sub = 0; sub < 4; ++sub) {
        int i0 = (sub >> 1) << 1;      // 0,0,2,2
        int j0 = (sub & 1) << 1;       // 0,2,0,2
        #pragma unroll
        for (int jj = 0; jj < 2; ++jj) {
            #pragma unroll
            for (int ii = 0; ii < 2; ++ii) {
                #pragma unroll
                for (int rr = 0; rr < 4; ++rr) {
                    int rl = ii * 16 + quad * 4 + rr;
                    int cl = jj * 16 + m16;
                    unsigned short hv =
                        f2bf((acc[i0 + ii][j0 + jj][rr] + bv[j0 + jj]) * sc);
                    if (!isV) wbuf[rl * 40 + cl] = hv;      // [row][col]
                    else      wbuf[cl * 40 + rl] = hv;      // [col][row]
                }
            }
        }
        __builtin_amdgcn_sched_barrier(0);
        if (!isV) {
            #pragma unroll
            for (int it = 0; it < 4; ++it) {
                int rl = it * 8 + (lane >> 3);
                int cc = (lane & 7) << 2;
                uint2 v2 = *(const uint2*)&wbuf[rl * 40 + cc];
                int rowg = row0 + wm * 64 + i0 * 16 + rl;
                int colg = col0 + wn * 64 + j0 * 16 + cc;
                *(uint2*)&qkv[(size_t)rowg * (2 * C_) + colg] = v2;
            }
        } else {
            #pragma unroll
            for (int it = 0; it < 4; ++it) {
                int dsub = it * 8 + (lane >> 3);
                int tc = (lane & 7) << 2;
                uint2 v2 = *(const uint2*)&wbuf[dsub * 40 + tc];
                int d = j0 * 16 + dsub;
                int tg = trow0 + i0 * 16 + tc;
                *(uint2*)&vtb[(size_t)d * T_ + tg] = v2;
            }
        }
        __builtin_amdgcn_sched_barrier(0);
    }
}

// ---------------------------------------------------------------------------
// GEMM2: out[M][C] (fp32) = A[M][K=C] (bf16, row stride 2C) @ w_proj_t^T + b
// ---------------------------------------------------------------------------
__global__ __launch_bounds__(256, 2)
void gemm_out(const unsigned short* __restrict__ A,
              const unsigned short* __restrict__ Bt,
              const float* __restrict__ bias,
              float* __restrict__ Cmat,
              int M) {
    const int N = C_;
    __shared__ __align__(16) unsigned short smem[32768];
    GEMM128_CORE(A, (2 * C_), Bt)

    #pragma unroll
    for (int j = 0; j < 4; ++j) {
        int col = col0 + wn * 64 + j * 16 + m16;
        float bvv = bias[col];
        #pragma unroll
        for (int i = 0; i < 4; ++i) {
            int row = row0 + wm * 64 + i * 16 + quad * 4;
            #pragma unroll
            for (int rr = 0; rr < 4; ++rr)
                Cmat[(size_t)(row + rr) * N + col] = acc[i][j][rr] + bvv;
        }
    }
}

// ---------------------------------------------------------------------------
// MFMA causal flash attention. QBLK=128 per block (each of 4 waves owns 32
// q-rows = two 16-row fragments) over 64-key K-tiles: fixed per-tile costs
// (staging, vmcnt drain, barrier, dep-chain latency) amortized over 2x MFMA.
// K/V staged via global_load_lds w/ pre-swizzled source (both-sides XOR);
// one raw s_barrier + vmcnt(0) per K-tile; native bf16 cast in softmax.
// ---------------------------------------------------------------------------
__global__ __launch_bounds__(256, 3)
void attn_mfma(unsigned short* __restrict__ qkv,
               const unsigned short* __restrict__ vt) {
    __shared__ __align__(16) unsigned short Ks[2][64][64];   // [buf][key][d]  16 KiB
    __shared__ __align__(16) unsigned short Vs[2][64][64];   // [buf][d][key]  16 KiB
    __shared__ __align__(16) unsigned short Pb[4][32][72];   // per-wave [qr][key] 18 KiB

    int bh = blockIdx.x;
    int b = bh >> 4, h = bh & 15;
    int qb = (T_ / 128 - 1) - blockIdx.y;    // 0..15 reversed: big blocks first
    int tid = threadIdx.x;
    int wave = tid >> 6;
    int lane = tid & 63;
    int m16 = lane & 15, quad = lane >> 4;

    const size_t rs = 2 * C_;
    unsigned short* base = qkv + (size_t)b * T_ * rs + h * 64;
    const unsigned short* kb0 = base + C_;
    const unsigned short* vtb = vt + (size_t)bh * 64 * T_;

    // Q: two 16-row fragments per wave (rows qb*128 + wave*32 + f*16 + m16)
    bf16x8 qf0[2], qf1[2];
    #pragma unroll
    for (int f = 0; f < 2; ++f) {
        int qrow = qb * 128 + wave * 32 + f * 16 + m16;
        const unsigned short* qp = base + (size_t)qrow * rs;
        qf0[f] = *(const bf16x8*)(qp + quad * 8);
        qf1[f] = *(const bf16x8*)(qp + 32 + quad * 8);
    }

    f32x4 o[2][4];
    #pragma unroll
    for (int f = 0; f < 2; ++f)
        #pragma unroll
        for (int dt = 0; dt < 4; ++dt) o[f][dt] = (f32x4){0.f, 0.f, 0.f, 0.f};
    float lrow[2][4] = {{0.f, 0.f, 0.f, 0.f}, {0.f, 0.f, 0.f, 0.f}};

    int qg0[2];
    qg0[0] = qb * 128 + wave * 32 + quad * 4;
    qg0[1] = qg0[0] + 16;

    int ntiles = 2 * qb + 2;

    // staging: row = tid>>3 (0..31) and +32; pre-swizzled global source
    int srow = tid >> 3;
    int schs = ((tid & 7) ^ (srow & 7)) * 8;
    const unsigned short* kps = kb0 + (size_t)srow * rs + schs;
    const unsigned short* vps = vtb + (size_t)srow * T_ + schs;
    unsigned short* kdst = &Ks[0][0][0] + wave * 512;   // +buf*4096 u16
    unsigned short* vdst = &Vs[0][0][0] + wave * 512;

    auto STAGE = [&](int kt, int buf) {
        const unsigned short* ks = kps + (size_t)(kt * 64) * rs;
        const unsigned short* vs = vps + kt * 64;
        unsigned short* kd = kdst + buf * 4096;
        unsigned short* vd = vdst + buf * 4096;
        gl_lds16(ks, kd);
        gl_lds16(ks + (size_t)32 * rs, kd + 2048);
        gl_lds16(vs, vd);
        gl_lds16(vs + (size_t)32 * T_, vd + 2048);
    };

    // read-side swizzled chunk offsets (row&7 == m16&7 for all our rows)
    int kpc0 = ((0 + quad) ^ (m16 & 7)) << 3;
    int kpc1 = ((4 + quad) ^ (m16 & 7)) << 3;

    STAGE(0, 0);
    asm volatile("s_waitcnt vmcnt(0)" ::: "memory");
    __builtin_amdgcn_s_barrier();

    for (int kt = 0; kt < ntiles; ++kt) {
        int cur = kt & 1;
        if (kt + 1 < ntiles) STAGE(kt + 1, cur ^ 1);

        // ---- QK^T: S[f][st] for 32 q-rows x 64 keys ----
        f32x4 s[2][4];
        #pragma unroll
        for (int st = 0; st < 4; ++st) {
            bf16x8 k0 = *(const bf16x8*)&Ks[cur][st * 16 + m16][kpc0];
            bf16x8 k1 = *(const bf16x8*)&Ks[cur][st * 16 + m16][kpc1];
            __builtin_amdgcn_s_setprio(1);
            #pragma unroll
            for (int f = 0; f < 2; ++f) {
                f32x4 a = (f32x4){0.f, 0.f, 0.f, 0.f};
                a = __builtin_amdgcn_mfma_f32_16x16x32_bf16(qf0[f], k0, a, 0, 0, 0);
                a = __builtin_amdgcn_mfma_f32_16x16x32_bf16(qf1[f], k1, a, 0, 0, 0);
                s[f][st] = a;
            }
            __builtin_amdgcn_s_setprio(0);
        }

        // ---- causal mask (only the last two k-tiles intersect the diag) ----
        if (kt >= 2 * qb) {
            #pragma unroll
            for (int f = 0; f < 2; ++f)
                #pragma unroll
                for (int st = 0; st < 4; ++st) {
                    int kg = kt * 64 + st * 16 + m16;
                    #pragma unroll
                    for (int r = 0; r < 4; ++r)
                        if (kg > qg0[f] + r) s[f][st][r] = -1.0e30f;
                }
        }

        // ---- softmax numerator: P = exp2(S), accumulate row sums ----
        #pragma unroll
        for (int f = 0; f < 2; ++f)
            #pragma unroll
            for (int st = 0; st < 4; ++st)
                #pragma unroll
                for (int r = 0; r < 4; ++r) {
                    float p = exp2_fast(s[f][st][r]);
                    lrow[f][r] += p;
                    Pb[wave][f * 16 + quad * 4 + r][st * 16 + m16] = f2bf_hw(p);
                }
        __builtin_amdgcn_sched_barrier(0);

        // ---- PV: o[f] += P[f] @ V ----
        #pragma unroll
        for (int s2 = 0; s2 < 2; ++s2) {
            int vpc = ((s2 * 4 + quad) ^ (m16 & 7)) << 3;
            #pragma unroll
            for (int f = 0; f < 2; ++f) {
                bf16x8 pa = *(const bf16x8*)&Pb[wave][f * 16 + m16][s2 * 32 + quad * 8];
                __builtin_amdgcn_s_setprio(1);
                #pragma unroll
                for (int dt = 0; dt < 4; ++dt) {
                    bf16x8 vv = *(const bf16x8*)&Vs[cur][dt * 16 + m16][vpc];
                    o[f][dt] = __builtin_amdgcn_mfma_f32_16x16x32_bf16(
                        pa, vv, o[f][dt], 0, 0, 0);
                }
                __builtin_amdgcn_s_setprio(0);
            }
        }

        asm volatile("s_waitcnt vmcnt(0)" ::: "memory");
        __builtin_amdgcn_s_barrier();
    }

    // ---- finalize: row-sum reduce over the 16 m16 lanes, scale, store ----
    #pragma unroll
    for (int f = 0; f < 2; ++f) {
        float lf[4];
        #pragma unroll
        for (int r = 0; r < 4; ++r) lf[r] = lrow[f][r];
        #pragma unroll
        for (int off = 1; off <= 8; off <<= 1)
            #pragma unroll
            for (int r = 0; r < 4; ++r)
                lf[r] += __shfl_xor(lf[r], off);

        #pragma unroll
        for (int r = 0; r < 4; ++r) {
            float inv = 1.0f / lf[r];
            unsigned short* op = base + (size_t)(qg0[f] + r) * rs;
            #pragma unroll
            for (int dt = 0; dt < 4; ++dt)
                op[dt * 16 + m16] = f2bf(o[f][dt][r] * inv);
        }
    }
}

// ---------------------------------------------------------------------------
extern "C" void kernel_launch(void* const* d_in, const int* in_sizes, int n_in,
                              void* d_out, int out_size, void* d_ws, size_t ws_size,
                              hipStream_t stream) {
    const float* x      = (const float*)d_in[0];
    const float* w_attn = (const float*)d_in[1];
    const float* b_attn = (const float*)d_in[2];
    const float* w_proj = (const float*)d_in[3];
    const float* b_proj = (const float*)d_in[4];
    float* out = (float*)d_out;

    unsigned short* ws = (unsigned short*)d_ws;
    unsigned short* xb       = ws;                               // [B*T][C]
    unsigned short* w_attn_t = xb + (size_t)B_ * T_ * C_;        // [3C][C]
    unsigned short* w_proj_t = w_attn_t + (size_t)3 * C_ * C_;   // [C][C]
    unsigned short* qkv      = w_proj_t + (size_t)C_ * C_;       // [bstep*T][2C]

    const size_t fixed_hw = (size_t)B_ * T_ * C_ + 4 * (size_t)C_ * C_;
    const size_t per_b_hw = (size_t)T_ * 2 * C_ + (size_t)H_ * 64 * T_; // qk + vt
    int bstep = (ws_size >= (fixed_hw + (size_t)B_ * per_b_hw) * sizeof(unsigned short))
                ? B_ : 1;

    int nx = B_ * T_ * C_;
    convert_f32_bf16<<<nx / 2048, 256, 0, stream>>>(x, xb, nx);
    transpose_f32_bf16<<<dim3(3 * C_ / 32, C_ / 32), dim3(32, 8), 0, stream>>>(
        w_attn, w_attn_t, C_, 3 * C_);
    transpose_f32_bf16<<<dim3(C_ / 32, C_ / 32), dim3(32, 8), 0, stream>>>(
        w_proj, w_proj_t, C_, C_);

    // q pre-scale: (1/sqrt(D)) * log2(e)  -> softmax via exp2, no max-sub
    const float QSCALE = 0.125f * 1.44269504088896341f;

    for (int b0 = 0; b0 < B_; b0 += bstep) {
        int M = bstep * T_;
        const unsigned short* xbb = xb + (size_t)b0 * T_ * C_;
        unsigned short* vt = qkv + (size_t)bstep * T_ * 2 * C_;  // [bstep*H][64][T]

        gemm_qkv<<<dim3(3 * C_ / BN, M / BM), 256, 0, stream>>>(
            xbb, w_attn_t, b_attn, qkv, vt, M, QSCALE);

        attn_mfma<<<dim3(bstep * H_, T_ / 128), 256, 0, stream>>>(qkv, vt);

        gemm_out<<<dim3(C_ / BN, M / BM), 256, 0, stream>>>(
            qkv, w_proj_t, b_proj, out + (size_t)b0 * T_ * C_, M);
    }
}